// Round 3
// baseline (552.362 us; speedup 1.0000x reference)
//
#include <hip/hip_runtime.h>

#define NN 2304
#define CC 192
#define NBATCH 16

typedef unsigned short u16;
typedef __bf16 bf16x8 __attribute__((ext_vector_type(8)));
typedef float f32x4 __attribute__((ext_vector_type(4)));
typedef float f32x16 __attribute__((ext_vector_type(16)));

__device__ __forceinline__ u16 bf16bits(float f) {
  union { float f; unsigned u; } v;
  v.f = f;
  unsigned r = v.u + 0x7FFFu + ((v.u >> 16) & 1u);
  return (u16)(r >> 16);
}

// XOR-swizzled LDS element index for a [rows][192] bf16 tile (row stride 192).
__device__ __forceinline__ int swzK(int row, int col) {
  int ch = col >> 3;
  int phys = (ch & ~7) | ((ch ^ row) & 7);
  return row * 192 + (phys << 3) + (col & 7);
}
// Same for [rows][64] bf16 tiles (8 chunks per row).
__device__ __forceinline__ int swz64(int row, int col) {
  int ch = (col >> 3) ^ row;
  return (row << 6) | ((ch & 7) << 3) | (col & 7);
}

// direct global->LDS 16B DMA; dest = wave-uniform base + lane*16
__device__ __forceinline__ void gll16(const u16* g, u16* l) {
  __builtin_amdgcn_global_load_lds(
      (const __attribute__((address_space(1))) u16*)g,
      (__attribute__((address_space(3))) u16*)l, 16, 0, 0);
}

// ---------------------------------------------------------------------------
// Kernel 1: LayerNorm over C, x[b,c,n] (fp32) -> xn[(b*N+n), c] (bf16)
// ---------------------------------------------------------------------------
__global__ __launch_bounds__(256) void ln_kernel(
    const float* __restrict__ x, const float* __restrict__ lnw,
    const float* __restrict__ lnb, u16* __restrict__ xn) {
  __shared__ float xt[192 * 65];
  __shared__ float psum[4][64], psq[4][64];
  __shared__ float mu_s[64], rs_s[64];
  __shared__ float lw_s[192], lb_s[192];
  int t = threadIdx.x;
  int b = blockIdx.y, n0 = blockIdx.x * 64;
  const float* xb = x + (size_t)b * CC * NN;
  if (t < 192) { lw_s[t] = lnw[t]; lb_s[t] = lnb[t]; }
#pragma unroll
  for (int i = 0; i < 48; ++i) {
    int idx = i * 256 + t;
    int c = idx >> 6, n = idx & 63;
    xt[c * 65 + n] = xb[(size_t)c * NN + n0 + n];
  }
  __syncthreads();
  {
    int n = t & 63, part = t >> 6;
    float s = 0.f, s2 = 0.f;
#pragma unroll
    for (int c = part * 48; c < part * 48 + 48; ++c) {
      float v = xt[c * 65 + n];
      s += v; s2 += v * v;
    }
    psum[part][n] = s; psq[part][n] = s2;
  }
  __syncthreads();
  if (t < 64) {
    float s = psum[0][t] + psum[1][t] + psum[2][t] + psum[3][t];
    float s2 = psq[0][t] + psq[1][t] + psq[2][t] + psq[3][t];
    float mu = s * (1.0f / 192.0f);
    float var = s2 * (1.0f / 192.0f) - mu * mu;
    mu_s[t] = mu;
    rs_s[t] = rsqrtf(var + 1e-5f);
  }
  __syncthreads();
#pragma unroll
  for (int i = 0; i < 12; ++i) {
    int u = i * 256 + t;
    int n = u / 48, cq = (u % 48) * 4;
    float mu = mu_s[n], rs = rs_s[n];
    alignas(8) u16 tmp[4];
#pragma unroll
    for (int k2 = 0; k2 < 4; ++k2) {
      float v = (xt[(cq + k2) * 65 + n] - mu) * rs * lw_s[cq + k2] + lb_s[cq + k2];
      tmp[k2] = bf16bits(v);
    }
    *(uint2*)&xn[((size_t)(b * NN + n0 + n)) * CC + cq] = *(uint2*)tmp;
  }
}

// ---------------------------------------------------------------------------
// Kernel 2: QKV projections. y = xn @ W^T. 64x64 tiles, K=192.
// z==2 (V) writes transposed: vt[b][d][n].
// ---------------------------------------------------------------------------
__global__ __launch_bounds__(256, 3) void qkv_gemm(
    const u16* __restrict__ xn, const float* __restrict__ Wq,
    const float* __restrict__ Wk, const float* __restrict__ Wv,
    u16* __restrict__ qb, u16* __restrict__ kb, u16* __restrict__ vtb) {
  __shared__ u16 xs[12288];
  __shared__ u16 wsm[12288];
  int t = threadIdx.x, w = t >> 6, lane = t & 63, l15 = lane & 15, qd = lane >> 4;
  int m0 = blockIdx.x * 64, n0 = blockIdx.y * 64, z = blockIdx.z;
  const float* W = (z == 0) ? Wq : (z == 1 ? Wk : Wv);
#pragma unroll
  for (int i = 0; i < 6; ++i) {
    int ch = i * 256 + t;
    int row = ch / 24, cin = (ch % 24) * 8;
    *(uint4*)&xs[swzK(row, cin)] = *(const uint4*)&xn[(size_t)(m0 + row) * 192 + cin];
  }
#pragma unroll
  for (int i = 0; i < 6; ++i) {
    int ch = i * 256 + t;
    int row = ch / 24, cin = (ch % 24) * 8;
    const float* src = &W[(size_t)(n0 + row) * 192 + cin];
    alignas(16) u16 tmp[8];
#pragma unroll
    for (int j = 0; j < 8; ++j) tmp[j] = bf16bits(src[j]);
    *(uint4*)&wsm[swzK(row, cin)] = *(uint4*)tmp;
  }
  __syncthreads();
  bf16x8 a[6];
#pragma unroll
  for (int kk = 0; kk < 6; ++kk)
    a[kk] = *(const bf16x8*)&xs[swzK(w * 16 + l15, kk * 32 + qd * 8)];
  const f32x4 fz = {0.f, 0.f, 0.f, 0.f};
  f32x4 acc[4];
#pragma unroll
  for (int ct = 0; ct < 4; ++ct) {
    acc[ct] = fz;
#pragma unroll
    for (int kk = 0; kk < 6; ++kk) {
      bf16x8 bfr = *(const bf16x8*)&wsm[swzK(ct * 16 + l15, kk * 32 + qd * 8)];
      acc[ct] = __builtin_amdgcn_mfma_f32_16x16x32_bf16(a[kk], bfr, acc[ct], 0, 0, 0);
    }
  }
  if (z < 2) {
    u16* outp = (z == 0) ? qb : kb;
#pragma unroll
    for (int ct = 0; ct < 4; ++ct)
#pragma unroll
      for (int r = 0; r < 4; ++r) {
        int m = m0 + w * 16 + qd * 4 + r;
        outp[(size_t)m * 192 + n0 + ct * 16 + l15] = bf16bits(acc[ct][r]);
      }
  } else {
    __syncthreads();
#pragma unroll
    for (int ct = 0; ct < 4; ++ct)
#pragma unroll
      for (int r = 0; r < 4; ++r)
        xs[swz64(ct * 16 + l15, w * 16 + qd * 4 + r)] = bf16bits(acc[ct][r]);
    __syncthreads();
    int b = blockIdx.x / 36, nb = (blockIdx.x % 36) * 64;
#pragma unroll
    for (int i = 0; i < 16; ++i) {
      int idx = i * 256 + t;
      int d = idx >> 6, nn = idx & 63;
      vtb[(size_t)b * 192 * NN + (size_t)(n0 + d) * NN + nb + nn] = xs[swz64(d, nn)];
    }
  }
}

// ---------------------------------------------------------------------------
// Kernel 3: fused flash attention v3 (fixed: LDS buffer select by offset,
// no array-of-LDS-pointers).
//   - K B-frags loaded DIRECTLY global->VGPR (no K LDS, no staging barrier)
//   - V double-buffered in LDS via global_load_lds; __syncthreads only ever
//     drains V loads that are a full phase (~S+P+PV) old
//   - packed P (lo=exp, hi=relu^2) in single 16KB LDS buffer
//   - one __syncthreads + one raw lgkm-only barrier per iter
//   - XCD batch clustering: XCD x runs batch 2x's 36 tiles, then 2x+1's
// ---------------------------------------------------------------------------
__global__ __launch_bounds__(256, 2) void attn_kernel(
    const u16* __restrict__ qb, const u16* __restrict__ kb,
    const u16* __restrict__ vtb, const float* __restrict__ w1p,
    const float* __restrict__ w2p, const float* __restrict__ x,
    float* __restrict__ out) {
  __shared__ u16 sm[32768];                 // 64 KB: V dbuf 2x24K | pu 16K
  uint32_t* pu = (uint32_t*)(sm + 24576);   // [64 q][64 k] packed u32
  float* lbuf = (float*)(sm + 24576);       // epilogue overlay (pu region)
  float* olds = (float*)sm;                 // epilogue overlay [192][64] f32

  int t = threadIdx.x, w = t >> 6, lane = t & 63;
  int l31 = lane & 31, hi = lane >> 5;
  int qh = w >> 1, ch = w & 1;
  int bid = blockIdx.x;
  int xcd = bid & 7, j = bid >> 3;          // XCD = bid%8 (round-robin dispatch)
  int b = xcd * 2 + (j >= 36 ? 1 : 0);      // one batch at a time per XCD
  int qt = (j >= 36) ? j - 36 : j;

  const u16* Kg = kb + (size_t)b * NN * CC;
  const u16* Vg = vtb + (size_t)b * CC * NN;

  // ---- Q A-frags direct from global (resident 48 VGPR) ----
  const u16* Qr = qb + ((size_t)b * NN + qt * 64 + qh * 32 + l31) * CC + hi * 8;
  bf16x8 qf[12];
#pragma unroll
  for (int ks = 0; ks < 12; ++ks) qf[ks] = *(const bf16x8*)(Qr + ks * 16);

  // ---- issue V(0) into buffer 0 ----
#pragma unroll
  for (int i = 0; i < 6; ++i) {
    int cid = i * 4 + w, sc = cid * 64 + lane;
    int d = sc >> 3, pc = sc & 7, gc = (pc ^ d) & 7;
    gll16(Vg + (size_t)d * NN + gc * 8, sm + cid * 512);
  }

  f32x16 z16;
#pragma unroll
  for (int i = 0; i < 16; ++i) z16[i] = 0.f;
  f32x16 os[3], orl[3];
#pragma unroll
  for (int i = 0; i < 3; ++i) { os[i] = z16; orl[i] = z16; }
  float lsum[16];
#pragma unroll
  for (int i = 0; i < 16; ++i) lsum[i] = 0.f;

  // K B-frag base for this wave (k-col = ch*32 + l31)
  const u16* Kw = Kg + ((size_t)(ch * 32 + l31)) * CC + hi * 8;

  for (int kt = 0; kt < 36; ++kt) {
    // ---- S(kt): K frags straight from global (L2-resident), 12 MFMA ----
    const u16* kp = Kw + (size_t)kt * 64 * CC;
    bf16x8 kf[12];
#pragma unroll
    for (int ks = 0; ks < 12; ++ks) kf[ks] = *(const bf16x8*)(kp + ks * 16);
    f32x16 s0 = z16, s1 = z16;
    __builtin_amdgcn_s_setprio(1);
#pragma unroll
    for (int ks = 0; ks < 6; ++ks) {
      s0 = __builtin_amdgcn_mfma_f32_32x32x16_bf16(qf[2 * ks], kf[2 * ks], s0, 0, 0, 0);
      s1 = __builtin_amdgcn_mfma_f32_32x32x16_bf16(qf[2 * ks + 1], kf[2 * ks + 1], s1, 0, 0, 0);
    }
    __builtin_amdgcn_s_setprio(0);

    // ---- P(kt): exp / relu^2, packed u32 -> pu ----
#pragma unroll
    for (int r = 0; r < 16; ++r) {
      float s = s0[r] + s1[r];
      float e = __expf(fminf(s, 60.f));
      float rl = (s > 0.f) ? s * s : 0.f;
      lsum[r] += e;
      int m = (r & 3) + 8 * (r >> 2) + 4 * hi;   // local q row 0..31
      int qL = qh * 32 + m;
      int c = ch * 32 + l31;                     // k col 0..63
      int chk = c >> 2;
      int phys = (chk & 8) | ((chk ^ (qL & 7)) & 7);
      pu[qL * 64 + phys * 4 + (c & 3)] =
          ((uint32_t)bf16bits(rl) << 16) | (uint32_t)bf16bits(e);
    }

    // barrier A: drains V(kt) (issued a full iter ago -> hidden), pu visible
    __syncthreads();

    // ---- issue V(kt+1) into the other buffer (flies under PV + next S/P) ----
    if (kt + 1 < 36) {
      u16* vdst = sm + ((kt + 1) & 1) * 12288;
#pragma unroll
      for (int i = 0; i < 6; ++i) {
        int cid = i * 4 + w, sc = cid * 64 + lane;
        int d = sc >> 3, pc = sc & 7, gc = (pc ^ d) & 7;
        gll16(Vg + (size_t)d * NN + (kt + 1) * 64 + gc * 8, vdst + cid * 512);
      }
    }

    // ---- PV(kt): O += P @ V for both branches ----
    const u16* vl = sm + (kt & 1) * 12288;
    __builtin_amdgcn_s_setprio(1);
#pragma unroll
    for (int ks4 = 0; ks4 < 4; ++ks4) {
      int qL = qh * 32 + l31;
      int c0 = 4 * ks4 + 2 * hi;
      int p0 = (c0 & 8) | ((c0 ^ (l31 & 7)) & 7);
      int c1 = c0 + 1;
      int p1 = (c1 & 8) | ((c1 ^ (l31 & 7)) & 7);
      uint32_t W[8];
      *(uint4*)&W[0] = *(const uint4*)&pu[qL * 64 + p0 * 4];
      *(uint4*)&W[4] = *(const uint4*)&pu[qL * 64 + p1 * 4];
      bf16x8 pfs, pfr;
      uint32_t* pw = (uint32_t*)&pfs;
      uint32_t* rw = (uint32_t*)&pfr;
#pragma unroll
      for (int p = 0; p < 4; ++p) {
        pw[p] = (W[2 * p] & 0xFFFFu) | (W[2 * p + 1] << 16);
        rw[p] = (W[2 * p] >> 16) | (W[2 * p + 1] & 0xFFFF0000u);
      }
#pragma unroll
      for (int dt = 0; dt < 3; ++dt) {
        bf16x8 vf = *(const bf16x8*)&vl[swz64((ch * 3 + dt) * 32 + l31, ks4 * 16 + hi * 8)];
        os[dt] = __builtin_amdgcn_mfma_f32_32x32x16_bf16(pfs, vf, os[dt], 0, 0, 0);
        orl[dt] = __builtin_amdgcn_mfma_f32_32x32x16_bf16(pfr, vf, orl[dt], 0, 0, 0);
      }
    }
    __builtin_amdgcn_s_setprio(0);

    // barrier B: protect pu (rewritten next iter); lgkm-only so V(kt+1)
    // gll stays in flight (counted-vmcnt style).
    asm volatile("s_waitcnt lgkmcnt(0)\ns_barrier" ::: "memory");
  }

  // ---- epilogue ----
  float e1 = __expf(w1p[0]), e2 = __expf(w2p[0]);
  float den = e1 + e2, c1f = e1 / den, c2f = e2 / den;
#pragma unroll
  for (int r = 0; r < 16; ++r) {
    float v = lsum[r];
    v += __shfl_xor(v, 1);
    v += __shfl_xor(v, 2);
    v += __shfl_xor(v, 4);
    v += __shfl_xor(v, 8);
    v += __shfl_xor(v, 16);
    lsum[r] = v;
  }
  if (l31 == 0) {
#pragma unroll
    for (int r = 0; r < 16; ++r) {
      int m = (r & 3) + 8 * (r >> 2) + 4 * hi;
      lbuf[(qh * 32 + m) * 2 + ch] = lsum[r];
    }
  }
  __syncthreads();
  float inv[16];
#pragma unroll
  for (int r = 0; r < 16; ++r) {
    int m = (r & 3) + 8 * (r >> 2) + 4 * hi;
    int q = qh * 32 + m;
    inv[r] = c1f / (lbuf[q * 2] + lbuf[q * 2 + 1]);
  }
  __syncthreads();  // all lbuf reads complete before olds overlay writes
  // blend + transpose into olds[d][q'] (q' = lane-XOR swizzle, conflict-free)
#pragma unroll
  for (int dt = 0; dt < 3; ++dt) {
    int d = (ch * 3 + dt) * 32 + l31;
#pragma unroll
    for (int r = 0; r < 16; ++r) {
      int m = (r & 3) + 8 * (r >> 2) + 4 * hi;
      int q = qh * 32 + m;
      olds[d * 64 + ((q & ~31) | ((q ^ d) & 31))] = os[dt][r] * inv[r] + c2f * orl[dt][r];
    }
  }
  __syncthreads();
  const float* xb = x + (size_t)b * CC * NN + qt * 64;
  float* ob = out + (size_t)b * CC * NN + qt * 64;
#pragma unroll
  for (int i = 0; i < 48; ++i) {
    int idx = i * 256 + t;
    int c = idx >> 6, nn = idx & 63;
    float v = olds[c * 64 + ((nn & ~31) | ((nn ^ c) & 31))];
    ob[(size_t)c * NN + nn] = v + xb[(size_t)c * NN + nn];
  }
}

// ---------------------------------------------------------------------------
extern "C" void kernel_launch(void* const* d_in, const int* in_sizes, int n_in,
                              void* d_out, int out_size, void* d_ws, size_t ws_size,
                              hipStream_t stream) {
  (void)in_sizes; (void)n_in; (void)out_size; (void)ws_size;
  const float* x   = (const float*)d_in[0];
  const float* lnw = (const float*)d_in[1];
  const float* lnb = (const float*)d_in[2];
  const float* Wq  = (const float*)d_in[3];
  const float* Wk  = (const float*)d_in[4];
  const float* Wv  = (const float*)d_in[5];
  const float* w1  = (const float*)d_in[6];
  const float* w2  = (const float*)d_in[7];
  float* out = (float*)d_out;

  u16* xn = (u16*)d_ws;
  size_t per = (size_t)NBATCH * NN * CC;
  u16* qb  = xn + per;
  u16* kb  = qb + per;
  u16* vtb = kb + per;

  ln_kernel<<<dim3(36, 16), 256, 0, stream>>>(x, lnw, lnb, xn);
  qkv_gemm<<<dim3(576, 3, 3), 256, 0, stream>>>(xn, Wq, Wk, Wv, qb, kb, vtb);
  attn_kernel<<<dim3(576), 256, 0, stream>>>(qb, kb, vtb, w1, w2, x, out);
}

// Round 5
// 517.880 us; speedup vs baseline: 1.0666x; 1.0666x over previous
//
#include <hip/hip_runtime.h>

#define NN 2304
#define CC 192
#define NBATCH 16

typedef unsigned short u16;
typedef __bf16 bf16x8 __attribute__((ext_vector_type(8)));
typedef float f32x4 __attribute__((ext_vector_type(4)));
typedef float f32x16 __attribute__((ext_vector_type(16)));

__device__ __forceinline__ u16 bf16bits(float f) {
  union { float f; unsigned u; } v;
  v.f = f;
  unsigned r = v.u + 0x7FFFu + ((v.u >> 16) & 1u);
  return (u16)(r >> 16);
}

// XOR-swizzled LDS element index for a [rows][192] bf16 tile (row stride 192).
__device__ __forceinline__ int swzK(int row, int col) {
  int ch = col >> 3;
  int phys = (ch & ~7) | ((ch ^ row) & 7);
  return row * 192 + (phys << 3) + (col & 7);
}
// Same for [rows][64] bf16 tiles (8 chunks per row).
__device__ __forceinline__ int swz64(int row, int col) {
  int ch = (col >> 3) ^ row;
  return (row << 6) | ((ch & 7) << 3) | (col & 7);
}

// direct global->LDS 16B DMA; dest = wave-uniform base + lane*16
__device__ __forceinline__ void gll16(const u16* g, u16* l) {
  __builtin_amdgcn_global_load_lds(
      (const __attribute__((address_space(1))) u16*)g,
      (__attribute__((address_space(3))) u16*)l, 16, 0, 0);
}

// ---------------------------------------------------------------------------
// Kernel 1: LayerNorm over C, x[b,c,n] (fp32) -> xn[(b*N+n), c] (bf16)
// ---------------------------------------------------------------------------
__global__ __launch_bounds__(256) void ln_kernel(
    const float* __restrict__ x, const float* __restrict__ lnw,
    const float* __restrict__ lnb, u16* __restrict__ xn) {
  __shared__ float xt[192 * 65];
  __shared__ float psum[4][64], psq[4][64];
  __shared__ float mu_s[64], rs_s[64];
  __shared__ float lw_s[192], lb_s[192];
  int t = threadIdx.x;
  int b = blockIdx.y, n0 = blockIdx.x * 64;
  const float* xb = x + (size_t)b * CC * NN;
  if (t < 192) { lw_s[t] = lnw[t]; lb_s[t] = lnb[t]; }
#pragma unroll
  for (int i = 0; i < 48; ++i) {
    int idx = i * 256 + t;
    int c = idx >> 6, n = idx & 63;
    xt[c * 65 + n] = xb[(size_t)c * NN + n0 + n];
  }
  __syncthreads();
  {
    int n = t & 63, part = t >> 6;
    float s = 0.f, s2 = 0.f;
#pragma unroll
    for (int c = part * 48; c < part * 48 + 48; ++c) {
      float v = xt[c * 65 + n];
      s += v; s2 += v * v;
    }
    psum[part][n] = s; psq[part][n] = s2;
  }
  __syncthreads();
  if (t < 64) {
    float s = psum[0][t] + psum[1][t] + psum[2][t] + psum[3][t];
    float s2 = psq[0][t] + psq[1][t] + psq[2][t] + psq[3][t];
    float mu = s * (1.0f / 192.0f);
    float var = s2 * (1.0f / 192.0f) - mu * mu;
    mu_s[t] = mu;
    rs_s[t] = rsqrtf(var + 1e-5f);
  }
  __syncthreads();
#pragma unroll
  for (int i = 0; i < 12; ++i) {
    int u = i * 256 + t;
    int n = u / 48, cq = (u % 48) * 4;
    float mu = mu_s[n], rs = rs_s[n];
    alignas(8) u16 tmp[4];
#pragma unroll
    for (int k2 = 0; k2 < 4; ++k2) {
      float v = (xt[(cq + k2) * 65 + n] - mu) * rs * lw_s[cq + k2] + lb_s[cq + k2];
      tmp[k2] = bf16bits(v);
    }
    *(uint2*)&xn[((size_t)(b * NN + n0 + n)) * CC + cq] = *(uint2*)tmp;
  }
}

// ---------------------------------------------------------------------------
// Kernel 2: QKV projections. y = xn @ W^T. 64x64 tiles, K=192.
// z==2 (V) writes transposed: vt[b][d][n].
// ---------------------------------------------------------------------------
__global__ __launch_bounds__(256, 3) void qkv_gemm(
    const u16* __restrict__ xn, const float* __restrict__ Wq,
    const float* __restrict__ Wk, const float* __restrict__ Wv,
    u16* __restrict__ qb, u16* __restrict__ kb, u16* __restrict__ vtb) {
  __shared__ u16 xs[12288];
  __shared__ u16 wsm[12288];
  int t = threadIdx.x, w = t >> 6, lane = t & 63, l15 = lane & 15, qd = lane >> 4;
  int m0 = blockIdx.x * 64, n0 = blockIdx.y * 64, z = blockIdx.z;
  const float* W = (z == 0) ? Wq : (z == 1 ? Wk : Wv);
#pragma unroll
  for (int i = 0; i < 6; ++i) {
    int ch = i * 256 + t;
    int row = ch / 24, cin = (ch % 24) * 8;
    *(uint4*)&xs[swzK(row, cin)] = *(const uint4*)&xn[(size_t)(m0 + row) * 192 + cin];
  }
#pragma unroll
  for (int i = 0; i < 6; ++i) {
    int ch = i * 256 + t;
    int row = ch / 24, cin = (ch % 24) * 8;
    const float* src = &W[(size_t)(n0 + row) * 192 + cin];
    alignas(16) u16 tmp[8];
#pragma unroll
    for (int j = 0; j < 8; ++j) tmp[j] = bf16bits(src[j]);
    *(uint4*)&wsm[swzK(row, cin)] = *(uint4*)tmp;
  }
  __syncthreads();
  bf16x8 a[6];
#pragma unroll
  for (int kk = 0; kk < 6; ++kk)
    a[kk] = *(const bf16x8*)&xs[swzK(w * 16 + l15, kk * 32 + qd * 8)];
  const f32x4 fz = {0.f, 0.f, 0.f, 0.f};
  f32x4 acc[4];
#pragma unroll
  for (int ct = 0; ct < 4; ++ct) {
    acc[ct] = fz;
#pragma unroll
    for (int kk = 0; kk < 6; ++kk) {
      bf16x8 bfr = *(const bf16x8*)&wsm[swzK(ct * 16 + l15, kk * 32 + qd * 8)];
      acc[ct] = __builtin_amdgcn_mfma_f32_16x16x32_bf16(a[kk], bfr, acc[ct], 0, 0, 0);
    }
  }
  if (z < 2) {
    u16* outp = (z == 0) ? qb : kb;
#pragma unroll
    for (int ct = 0; ct < 4; ++ct)
#pragma unroll
      for (int r = 0; r < 4; ++r) {
        int m = m0 + w * 16 + qd * 4 + r;
        outp[(size_t)m * 192 + n0 + ct * 16 + l15] = bf16bits(acc[ct][r]);
      }
  } else {
    __syncthreads();
#pragma unroll
    for (int ct = 0; ct < 4; ++ct)
#pragma unroll
      for (int r = 0; r < 4; ++r)
        xs[swz64(ct * 16 + l15, w * 16 + qd * 4 + r)] = bf16bits(acc[ct][r]);
    __syncthreads();
    int b = blockIdx.x / 36, nb = (blockIdx.x % 36) * 64;
#pragma unroll
    for (int i = 0; i < 16; ++i) {
      int idx = i * 256 + t;
      int d = idx >> 6, nn = idx & 63;
      vtb[(size_t)b * 192 * NN + (size_t)(n0 + d) * NN + nb + nn] = xs[swz64(d, nn)];
    }
  }
}

// ---------------------------------------------------------------------------
// Kernel 3a: pass 1 — softmax denominators. S^T = K·Q^T (swapped operands ->
// lane-local q cols), lsum[q] = sum_k exp(min(S,60)).
// ---------------------------------------------------------------------------
__global__ __launch_bounds__(256, 3) void attn_lsum(
    const u16* __restrict__ qb, const u16* __restrict__ kb,
    float* __restrict__ lsum_g) {
  __shared__ u16 sm[24576];        // K dbuf: 2 x [64][192] bf16 (swzK)
  __shared__ float lp[2][2][32];   // [qh][ch][q]
  int t = threadIdx.x, w = t >> 6, lane = t & 63;
  int l31 = lane & 31, hi = lane >> 5;
  int qh = w >> 1, ch = w & 1;
  int bid = blockIdx.x;
  int xcd = bid & 7, j = bid >> 3;
  int b = xcd * 2 + (j >= 36 ? 1 : 0);
  int qt = (j >= 36) ? j - 36 : j;

  const u16* Kg = kb + (size_t)b * NN * CC;
  const u16* Qr = qb + ((size_t)b * NN + qt * 64 + qh * 32 + l31) * CC + hi * 8;
  bf16x8 qf[12];
#pragma unroll
  for (int ks = 0; ks < 12; ++ks) qf[ks] = *(const bf16x8*)(Qr + ks * 16);

  // stage K(0) -> buf0
#pragma unroll
  for (int i = 0; i < 6; ++i) {
    int cid = i * 4 + w, sc = cid * 64 + lane;
    int row = sc / 24, pc = sc % 24;
    int gc = (pc & ~7) | ((pc ^ row) & 7);
    gll16(Kg + (size_t)row * CC + gc * 8, sm + cid * 512);
  }

  f32x16 z16;
#pragma unroll
  for (int i = 0; i < 16; ++i) z16[i] = 0.f;
  float lsum = 0.f;

  for (int kt = 0; kt < 36; ++kt) {
    asm volatile("s_waitcnt vmcnt(0) lgkmcnt(0)\ns_barrier" ::: "memory");
    if (kt + 1 < 36) {
      u16* dst = sm + ((kt + 1) & 1) * 12288;
#pragma unroll
      for (int i = 0; i < 6; ++i) {
        int cid = i * 4 + w, sc = cid * 64 + lane;
        int row = sc / 24, pc = sc % 24;
        int gc = (pc & ~7) | ((pc ^ row) & 7);
        gll16(Kg + ((size_t)(kt + 1) * 64 + row) * CC + gc * 8, dst + cid * 512);
      }
    }
    const u16* kl = sm + (kt & 1) * 12288;
    f32x16 s0 = z16, s1 = z16;
    __builtin_amdgcn_s_setprio(1);
#pragma unroll
    for (int ks = 0; ks < 6; ++ks) {
      bf16x8 k0 = *(const bf16x8*)&kl[swzK(ch * 32 + l31, (2 * ks) * 16 + hi * 8)];
      bf16x8 k1 = *(const bf16x8*)&kl[swzK(ch * 32 + l31, (2 * ks + 1) * 16 + hi * 8)];
      s0 = __builtin_amdgcn_mfma_f32_32x32x16_bf16(k0, qf[2 * ks], s0, 0, 0, 0);
      s1 = __builtin_amdgcn_mfma_f32_32x32x16_bf16(k1, qf[2 * ks + 1], s1, 0, 0, 0);
    }
    __builtin_amdgcn_s_setprio(0);
#pragma unroll
    for (int r = 0; r < 16; ++r) {
      float s = s0[r] + s1[r];
      lsum += __expf(fminf(s, 60.f));
    }
  }
  lsum += __shfl_xor(lsum, 32);
  if (lane < 32) lp[qh][ch][l31] = lsum;
  __syncthreads();
  if (w == 0) {
    lsum_g[(size_t)b * NN + qt * 64 + lane] =
        lp[lane >> 5][0][lane & 31] + lp[lane >> 5][1][lane & 31];
  }
}

// ---------------------------------------------------------------------------
// Kernel 3b: pass 2 — blended single-accumulator PV.
// FIX vs R4: each wave computes S^T for BOTH k-blocks (kb=0,1; 24 MFMAs),
// so PV sums the full 64-k tile (4 k-16 MFMAs per dt). Blend in f32:
// p = (c1/l)*exp + c2*relu^2; pack to bf16 A-frags in-register (shfl_xor(32)).
// Pipeline unchanged: 3-barrier counted-vmcnt, K/V single-buffered.
// ---------------------------------------------------------------------------
__global__ __launch_bounds__(256, 3) void attn_pv(
    const u16* __restrict__ qb, const u16* __restrict__ kb,
    const u16* __restrict__ vtb, const float* __restrict__ lsum_g,
    const float* __restrict__ w1p, const float* __restrict__ w2p,
    const float* __restrict__ x, float* __restrict__ out) {
  __shared__ u16 sm[24576];        // K [64][192] @0 (24K) | V^T [192][64] @12288 (24K)
  float* olds = (float*)sm;        // epilogue overlay [192][64] f32 (48K)

  int t = threadIdx.x, w = t >> 6, lane = t & 63;
  int l31 = lane & 31, hi = lane >> 5;
  int qh = w >> 1, ch = w & 1;
  int bid = blockIdx.x;
  int xcd = bid & 7, j = bid >> 3;
  int b = xcd * 2 + (j >= 36 ? 1 : 0);
  int qt = (j >= 36) ? j - 36 : j;

  const u16* Kg = kb + (size_t)b * NN * CC;
  const u16* Vg = vtb + (size_t)b * CC * NN;
  const u16* Qr = qb + ((size_t)b * NN + qt * 64 + qh * 32 + l31) * CC + hi * 8;
  bf16x8 qf[12];
#pragma unroll
  for (int ks = 0; ks < 12; ++ks) qf[ks] = *(const bf16x8*)(Qr + ks * 16);

  float e1 = __expf(w1p[0]), e2 = __expf(w2p[0]);
  float den = e1 + e2;
  float c2f = e2 / den;
  float cl1 = (e1 / den) / lsum_g[(size_t)b * NN + qt * 64 + qh * 32 + l31];

  f32x16 z16;
#pragma unroll
  for (int i = 0; i < 16; ++i) z16[i] = 0.f;
  f32x16 os[3];
#pragma unroll
  for (int i = 0; i < 3; ++i) os[i] = z16;

#define STAGE_K(KT)                                                        \
  {                                                                        \
    _Pragma("unroll") for (int i = 0; i < 6; ++i) {                        \
      int cid = i * 4 + w, sc = cid * 64 + lane;                           \
      int row = sc / 24, pc = sc % 24;                                     \
      int gc = (pc & ~7) | ((pc ^ row) & 7);                               \
      gll16(Kg + ((size_t)(KT) * 64 + row) * CC + gc * 8, sm + cid * 512); \
    }                                                                      \
  }
#define STAGE_V(KT)                                                        \
  {                                                                        \
    _Pragma("unroll") for (int i = 0; i < 6; ++i) {                        \
      int cid = i * 4 + w, sc = cid * 64 + lane;                           \
      int d = sc >> 3, pc = sc & 7, gc = (pc ^ d) & 7;                     \
      gll16(Vg + (size_t)d * NN + (KT) * 64 + gc * 8,                      \
            sm + 12288 + cid * 512);                                       \
    }                                                                      \
  }

  uint32_t pA[4][4];  // 4 A-frags (k-blocks of 16), full 64-k coverage
  // S(kt) -> blended bf16 A-frags, BOTH 32-k halves (fix for R4 bug)
#define S_BLEND()                                                           \
  {                                                                         \
    _Pragma("unroll") for (int kblk = 0; kblk < 2; ++kblk) {                \
      f32x16 sA = z16;                                                      \
      __builtin_amdgcn_s_setprio(1);                                        \
      _Pragma("unroll") for (int ks = 0; ks < 12; ++ks) {                   \
        bf16x8 kf =                                                         \
            *(const bf16x8*)&sm[swzK(kblk * 32 + l31, ks * 16 + hi * 8)];   \
        sA = __builtin_amdgcn_mfma_f32_32x32x16_bf16(kf, qf[ks], sA, 0, 0, 0); \
      }                                                                     \
      __builtin_amdgcn_s_setprio(0);                                        \
      uint32_t W[8];                                                        \
      _Pragma("unroll") for (int g = 0; g < 4; ++g) {                       \
        float sv0 = sA[4 * g + 0], sv1 = sA[4 * g + 1];                     \
        float sv2 = sA[4 * g + 2], sv3 = sA[4 * g + 3];                     \
        float p0 = cl1 * __expf(fminf(sv0, 60.f)) +                         \
                   c2f * ((sv0 > 0.f) ? sv0 * sv0 : 0.f);                   \
        float p1 = cl1 * __expf(fminf(sv1, 60.f)) +                         \
                   c2f * ((sv1 > 0.f) ? sv1 * sv1 : 0.f);                   \
        float p2 = cl1 * __expf(fminf(sv2, 60.f)) +                         \
                   c2f * ((sv2 > 0.f) ? sv2 * sv2 : 0.f);                   \
        float p3 = cl1 * __expf(fminf(sv3, 60.f)) +                         \
                   c2f * ((sv3 > 0.f) ? sv3 * sv3 : 0.f);                   \
        W[2 * g] = ((uint32_t)bf16bits(p1) << 16) | bf16bits(p0);           \
        W[2 * g + 1] = ((uint32_t)bf16bits(p3) << 16) | bf16bits(p2);       \
      }                                                                     \
      uint32_t X[8];                                                        \
      _Pragma("unroll") for (int jj = 0; jj < 8; ++jj)                      \
          X[jj] = __shfl_xor(W[jj], 32);                                    \
      pA[2 * kblk][0] = hi ? X[2] : W[0];                                   \
      pA[2 * kblk][1] = hi ? X[3] : W[1];                                   \
      pA[2 * kblk][2] = hi ? W[2] : X[0];                                   \
      pA[2 * kblk][3] = hi ? W[3] : X[1];                                   \
      pA[2 * kblk + 1][0] = hi ? X[6] : W[4];                               \
      pA[2 * kblk + 1][1] = hi ? X[7] : W[5];                               \
      pA[2 * kblk + 1][2] = hi ? W[6] : X[4];                               \
      pA[2 * kblk + 1][3] = hi ? W[7] : X[5];                               \
    }                                                                       \
  }

  // ---- prologue: K(0)+V(0) in flight; S(0) -> pA; issue K(1) ----
  STAGE_K(0);
  STAGE_V(0);
  asm volatile("s_waitcnt vmcnt(6)\ns_barrier" ::: "memory");  // K(0) landed
  S_BLEND();
  asm volatile("s_waitcnt lgkmcnt(0)\ns_barrier" ::: "memory"); // S reads done
  STAGE_K(1);

  for (int kt = 0; kt < 36; ++kt) {
    // A: V(kt) landed (6 newer K glls stay in flight)
    if (kt == 35)
      asm volatile("s_waitcnt vmcnt(0) lgkmcnt(0)\ns_barrier" ::: "memory");
    else
      asm volatile("s_waitcnt vmcnt(6) lgkmcnt(0)\ns_barrier" ::: "memory");

    // ---- PV(kt): os += P(kt) @ V(kt), full 64-k sum ----
    const u16* vl = sm + 12288;
    __builtin_amdgcn_s_setprio(1);
#pragma unroll
    for (int dt = 0; dt < 3; ++dt) {
      int d = ch * 96 + dt * 32 + l31;
#pragma unroll
      for (int kk = 0; kk < 4; ++kk) {
        bf16x8 vf = *(const bf16x8*)&vl[swz64(d, kk * 16 + hi * 8)];
        os[dt] = __builtin_amdgcn_mfma_f32_32x32x16_bf16(
            *(const bf16x8*)pA[kk], vf, os[dt], 0, 0, 0);
      }
    }
    __builtin_amdgcn_s_setprio(0);

    if (kt < 35) {
      // BC: PV reads done; K(kt+1) landed (only outstanding glls)
      asm volatile("s_waitcnt vmcnt(0) lgkmcnt(0)\ns_barrier" ::: "memory");
      STAGE_V(kt + 1);           // flies under S(kt+1) + next A
      S_BLEND();                 // S(kt+1) -> pA (P for next PV)
      // D: S reads done -> K region free
      asm volatile("s_waitcnt lgkmcnt(0)\ns_barrier" ::: "memory");
      if (kt + 2 < 36) STAGE_K(kt + 2);  // flies under PV(kt+1)
    }
  }

  // ---- epilogue: transpose via LDS overlay, residual add, coalesced store ----
  __syncthreads();
#pragma unroll
  for (int dt = 0; dt < 3; ++dt) {
    int d = ch * 96 + dt * 32 + l31;
#pragma unroll
    for (int r = 0; r < 16; ++r) {
      int m = (r & 3) + 8 * (r >> 2) + 4 * hi;
      int q = qh * 32 + m;
      olds[d * 64 + ((q & ~31) | ((q ^ d) & 31))] = os[dt][r];
    }
  }
  __syncthreads();
  const float* xb = x + (size_t)b * CC * NN + qt * 64;
  float* ob = out + (size_t)b * CC * NN + qt * 64;
#pragma unroll
  for (int i = 0; i < 48; ++i) {
    int idx = i * 256 + t;
    int c = idx >> 6, nn = idx & 63;
    float v = olds[c * 64 + ((nn & ~31) | ((nn ^ c) & 31))];
    ob[(size_t)c * NN + nn] = v + xb[(size_t)c * NN + nn];
  }
#undef STAGE_K
#undef STAGE_V
#undef S_BLEND
}

// ---------------------------------------------------------------------------
extern "C" void kernel_launch(void* const* d_in, const int* in_sizes, int n_in,
                              void* d_out, int out_size, void* d_ws, size_t ws_size,
                              hipStream_t stream) {
  (void)in_sizes; (void)n_in; (void)out_size; (void)ws_size;
  const float* x   = (const float*)d_in[0];
  const float* lnw = (const float*)d_in[1];
  const float* lnb = (const float*)d_in[2];
  const float* Wq  = (const float*)d_in[3];
  const float* Wk  = (const float*)d_in[4];
  const float* Wv  = (const float*)d_in[5];
  const float* w1  = (const float*)d_in[6];
  const float* w2  = (const float*)d_in[7];
  float* out = (float*)d_out;

  u16* xn = (u16*)d_ws;
  size_t per = (size_t)NBATCH * NN * CC;
  u16* qb  = xn + per;
  u16* kb  = qb + per;
  u16* vtb = kb + per;
  // lsum reuses the xn region (xn is dead after qkv_gemm; 147KB << 14MB)
  float* lsum_g = (float*)d_ws;

  ln_kernel<<<dim3(36, 16), 256, 0, stream>>>(x, lnw, lnb, xn);
  qkv_gemm<<<dim3(576, 3, 3), 256, 0, stream>>>(xn, Wq, Wk, Wv, qb, kb, vtb);
  attn_lsum<<<dim3(576), 256, 0, stream>>>(qb, kb, lsum_g);
  attn_pv<<<dim3(576), 256, 0, stream>>>(qb, kb, vtb, lsum_g, w1, w2, x, out);
}

// Round 6
// 345.807 us; speedup vs baseline: 1.5973x; 1.4976x over previous
//
#include <hip/hip_runtime.h>

#define NN 2304
#define CC 192
#define NBATCH 16

typedef unsigned short u16;
typedef __bf16 bf16x8 __attribute__((ext_vector_type(8)));
typedef float f32x4 __attribute__((ext_vector_type(4)));
typedef float f32x16 __attribute__((ext_vector_type(16)));

__device__ __forceinline__ u16 bf16bits(float f) {
  union { float f; unsigned u; } v;
  v.f = f;
  unsigned r = v.u + 0x7FFFu + ((v.u >> 16) & 1u);
  return (u16)(r >> 16);
}

// XOR-swizzled LDS element index for a [rows][192] bf16 tile (row stride 192).
__device__ __forceinline__ int swzK(int row, int col) {
  int ch = col >> 3;
  int phys = (ch & ~7) | ((ch ^ row) & 7);
  return row * 192 + (phys << 3) + (col & 7);
}
// Same for [rows][64] bf16 tiles (8 chunks per row).
__device__ __forceinline__ int swz64(int row, int col) {
  int ch = (col >> 3) ^ row;
  return (row << 6) | ((ch & 7) << 3) | (col & 7);
}

// direct global->LDS 16B DMA; dest = wave-uniform base + lane*16
__device__ __forceinline__ void gll16(const u16* g, u16* l) {
  __builtin_amdgcn_global_load_lds(
      (const __attribute__((address_space(1))) u16*)g,
      (__attribute__((address_space(3))) u16*)l, 16, 0, 0);
}

// ---------------------------------------------------------------------------
// Kernel 1: LayerNorm over C, x[b,c,n] (fp32) -> xn[(b*N+n), c] (bf16)
// ---------------------------------------------------------------------------
__global__ __launch_bounds__(256) void ln_kernel(
    const float* __restrict__ x, const float* __restrict__ lnw,
    const float* __restrict__ lnb, u16* __restrict__ xn) {
  __shared__ float xt[192 * 65];
  __shared__ float psum[4][64], psq[4][64];
  __shared__ float mu_s[64], rs_s[64];
  __shared__ float lw_s[192], lb_s[192];
  int t = threadIdx.x;
  int b = blockIdx.y, n0 = blockIdx.x * 64;
  const float* xb = x + (size_t)b * CC * NN;
  if (t < 192) { lw_s[t] = lnw[t]; lb_s[t] = lnb[t]; }
#pragma unroll
  for (int i = 0; i < 48; ++i) {
    int idx = i * 256 + t;
    int c = idx >> 6, n = idx & 63;
    xt[c * 65 + n] = xb[(size_t)c * NN + n0 + n];
  }
  __syncthreads();
  {
    int n = t & 63, part = t >> 6;
    float s = 0.f, s2 = 0.f;
#pragma unroll
    for (int c = part * 48; c < part * 48 + 48; ++c) {
      float v = xt[c * 65 + n];
      s += v; s2 += v * v;
    }
    psum[part][n] = s; psq[part][n] = s2;
  }
  __syncthreads();
  if (t < 64) {
    float s = psum[0][t] + psum[1][t] + psum[2][t] + psum[3][t];
    float s2 = psq[0][t] + psq[1][t] + psq[2][t] + psq[3][t];
    float mu = s * (1.0f / 192.0f);
    float var = s2 * (1.0f / 192.0f) - mu * mu;
    mu_s[t] = mu;
    rs_s[t] = rsqrtf(var + 1e-5f);
  }
  __syncthreads();
#pragma unroll
  for (int i = 0; i < 12; ++i) {
    int u = i * 256 + t;
    int n = u / 48, cq = (u % 48) * 4;
    float mu = mu_s[n], rs = rs_s[n];
    alignas(8) u16 tmp[4];
#pragma unroll
    for (int k2 = 0; k2 < 4; ++k2) {
      float v = (xt[(cq + k2) * 65 + n] - mu) * rs * lw_s[cq + k2] + lb_s[cq + k2];
      tmp[k2] = bf16bits(v);
    }
    *(uint2*)&xn[((size_t)(b * NN + n0 + n)) * CC + cq] = *(uint2*)tmp;
  }
}

// ---------------------------------------------------------------------------
// Kernel 2: QKV projections. y = xn @ W^T. 64x64 tiles, K=192.
// z==2 (V) writes transposed: vt[b][d][n].
// ---------------------------------------------------------------------------
__global__ __launch_bounds__(256, 3) void qkv_gemm(
    const u16* __restrict__ xn, const float* __restrict__ Wq,
    const float* __restrict__ Wk, const float* __restrict__ Wv,
    u16* __restrict__ qb, u16* __restrict__ kb, u16* __restrict__ vtb) {
  __shared__ u16 xs[12288];
  __shared__ u16 wsm[12288];
  int t = threadIdx.x, w = t >> 6, lane = t & 63, l15 = lane & 15, qd = lane >> 4;
  int m0 = blockIdx.x * 64, n0 = blockIdx.y * 64, z = blockIdx.z;
  const float* W = (z == 0) ? Wq : (z == 1 ? Wk : Wv);
#pragma unroll
  for (int i = 0; i < 6; ++i) {
    int ch = i * 256 + t;
    int row = ch / 24, cin = (ch % 24) * 8;
    *(uint4*)&xs[swzK(row, cin)] = *(const uint4*)&xn[(size_t)(m0 + row) * 192 + cin];
  }
#pragma unroll
  for (int i = 0; i < 6; ++i) {
    int ch = i * 256 + t;
    int row = ch / 24, cin = (ch % 24) * 8;
    const float* src = &W[(size_t)(n0 + row) * 192 + cin];
    alignas(16) u16 tmp[8];
#pragma unroll
    for (int j = 0; j < 8; ++j) tmp[j] = bf16bits(src[j]);
    *(uint4*)&wsm[swzK(row, cin)] = *(uint4*)tmp;
  }
  __syncthreads();
  bf16x8 a[6];
#pragma unroll
  for (int kk = 0; kk < 6; ++kk)
    a[kk] = *(const bf16x8*)&xs[swzK(w * 16 + l15, kk * 32 + qd * 8)];
  const f32x4 fz = {0.f, 0.f, 0.f, 0.f};
  f32x4 acc[4];
#pragma unroll
  for (int ct = 0; ct < 4; ++ct) {
    acc[ct] = fz;
#pragma unroll
    for (int kk = 0; kk < 6; ++kk) {
      bf16x8 bfr = *(const bf16x8*)&wsm[swzK(ct * 16 + l15, kk * 32 + qd * 8)];
      acc[ct] = __builtin_amdgcn_mfma_f32_16x16x32_bf16(a[kk], bfr, acc[ct], 0, 0, 0);
    }
  }
  if (z < 2) {
    u16* outp = (z == 0) ? qb : kb;
#pragma unroll
    for (int ct = 0; ct < 4; ++ct)
#pragma unroll
      for (int r = 0; r < 4; ++r) {
        int m = m0 + w * 16 + qd * 4 + r;
        outp[(size_t)m * 192 + n0 + ct * 16 + l15] = bf16bits(acc[ct][r]);
      }
  } else {
    __syncthreads();
#pragma unroll
    for (int ct = 0; ct < 4; ++ct)
#pragma unroll
      for (int r = 0; r < 4; ++r)
        xs[swz64(ct * 16 + l15, w * 16 + qd * 4 + r)] = bf16bits(acc[ct][r]);
    __syncthreads();
    int b = blockIdx.x / 36, nb = (blockIdx.x % 36) * 64;
#pragma unroll
    for (int i = 0; i < 16; ++i) {
      int idx = i * 256 + t;
      int d = idx >> 6, nn = idx & 63;
      vtb[(size_t)b * 192 * NN + (size_t)(n0 + d) * NN + nb + nn] = xs[swz64(d, nn)];
    }
  }
}

// ---------------------------------------------------------------------------
// Kernel 3a: pass 1 — softmax denominators. S^T = K·Q^T (swapped operands ->
// lane-local q cols), lsum[q] = sum_k exp(min(S,60)).
// ---------------------------------------------------------------------------
__global__ __launch_bounds__(256, 3) void attn_lsum(
    const u16* __restrict__ qb, const u16* __restrict__ kb,
    float* __restrict__ lsum_g) {
  __shared__ u16 sm[24576];        // K dbuf: 2 x [64][192] bf16 (swzK)
  __shared__ float lp[2][2][32];   // [qh][ch][q]
  int t = threadIdx.x, w = t >> 6, lane = t & 63;
  int l31 = lane & 31, hi = lane >> 5;
  int qh = w >> 1, ch = w & 1;
  int bid = blockIdx.x;
  int xcd = bid & 7, j = bid >> 3;
  int b = xcd * 2 + (j >= 36 ? 1 : 0);
  int qt = (j >= 36) ? j - 36 : j;

  const u16* Kg = kb + (size_t)b * NN * CC;
  const u16* Qr = qb + ((size_t)b * NN + qt * 64 + qh * 32 + l31) * CC + hi * 8;
  bf16x8 qf[12];
#pragma unroll
  for (int ks = 0; ks < 12; ++ks) qf[ks] = *(const bf16x8*)(Qr + ks * 16);

  // stage K(0) -> buf0
#pragma unroll
  for (int i = 0; i < 6; ++i) {
    int cid = i * 4 + w, sc = cid * 64 + lane;
    int row = sc / 24, pc = sc % 24;
    int gc = (pc & ~7) | ((pc ^ row) & 7);
    gll16(Kg + (size_t)row * CC + gc * 8, sm + cid * 512);
  }

  f32x16 z16;
#pragma unroll
  for (int i = 0; i < 16; ++i) z16[i] = 0.f;
  float lsum = 0.f;

  for (int kt = 0; kt < 36; ++kt) {
    asm volatile("s_waitcnt vmcnt(0) lgkmcnt(0)\ns_barrier" ::: "memory");
    if (kt + 1 < 36) {
      u16* dst = sm + ((kt + 1) & 1) * 12288;
#pragma unroll
      for (int i = 0; i < 6; ++i) {
        int cid = i * 4 + w, sc = cid * 64 + lane;
        int row = sc / 24, pc = sc % 24;
        int gc = (pc & ~7) | ((pc ^ row) & 7);
        gll16(Kg + ((size_t)(kt + 1) * 64 + row) * CC + gc * 8, dst + cid * 512);
      }
    }
    const u16* kl = sm + (kt & 1) * 12288;
    f32x16 s0 = z16, s1 = z16;
    __builtin_amdgcn_s_setprio(1);
#pragma unroll
    for (int ks = 0; ks < 6; ++ks) {
      bf16x8 k0 = *(const bf16x8*)&kl[swzK(ch * 32 + l31, (2 * ks) * 16 + hi * 8)];
      bf16x8 k1 = *(const bf16x8*)&kl[swzK(ch * 32 + l31, (2 * ks + 1) * 16 + hi * 8)];
      s0 = __builtin_amdgcn_mfma_f32_32x32x16_bf16(k0, qf[2 * ks], s0, 0, 0, 0);
      s1 = __builtin_amdgcn_mfma_f32_32x32x16_bf16(k1, qf[2 * ks + 1], s1, 0, 0, 0);
    }
    __builtin_amdgcn_s_setprio(0);
#pragma unroll
    for (int r = 0; r < 16; ++r) {
      float s = s0[r] + s1[r];
      lsum += __expf(fminf(s, 60.f));
    }
  }
  lsum += __shfl_xor(lsum, 32);
  if (lane < 32) lp[qh][ch][l31] = lsum;
  __syncthreads();
  if (w == 0) {
    lsum_g[(size_t)b * NN + qt * 64 + lane] =
        lp[lane >> 5][0][lane & 31] + lp[lane >> 5][1][lane & 31];
  }
}

// ---------------------------------------------------------------------------
// Kernel 3b: pass 2 — blended single-accumulator PV.
// R5 post-mortem fix: launch_bounds (256,3)->(256,2). The 170-reg unified cap
// at 3 waves/EU forced ~2.7KB/thread of scratch spill (WRITE_SIZE 399MB vs
// 28MB of real output). At 2 waves/EU the ~170-reg demand fits in the 256
// cap with headroom -> no spill. Everything else unchanged (clean A/B).
// ---------------------------------------------------------------------------
__global__ __launch_bounds__(256, 2) void attn_pv(
    const u16* __restrict__ qb, const u16* __restrict__ kb,
    const u16* __restrict__ vtb, const float* __restrict__ lsum_g,
    const float* __restrict__ w1p, const float* __restrict__ w2p,
    const float* __restrict__ x, float* __restrict__ out) {
  __shared__ u16 sm[24576];        // K [64][192] @0 (24K) | V^T [192][64] @12288 (24K)
  float* olds = (float*)sm;        // epilogue overlay [192][64] f32 (48K)

  int t = threadIdx.x, w = t >> 6, lane = t & 63;
  int l31 = lane & 31, hi = lane >> 5;
  int qh = w >> 1, ch = w & 1;
  int bid = blockIdx.x;
  int xcd = bid & 7, j = bid >> 3;
  int b = xcd * 2 + (j >= 36 ? 1 : 0);
  int qt = (j >= 36) ? j - 36 : j;

  const u16* Kg = kb + (size_t)b * NN * CC;
  const u16* Vg = vtb + (size_t)b * CC * NN;
  const u16* Qr = qb + ((size_t)b * NN + qt * 64 + qh * 32 + l31) * CC + hi * 8;
  bf16x8 qf[12];
#pragma unroll
  for (int ks = 0; ks < 12; ++ks) qf[ks] = *(const bf16x8*)(Qr + ks * 16);

  float e1 = __expf(w1p[0]), e2 = __expf(w2p[0]);
  float den = e1 + e2;
  float c2f = e2 / den;
  float cl1 = (e1 / den) / lsum_g[(size_t)b * NN + qt * 64 + qh * 32 + l31];

  f32x16 z16;
#pragma unroll
  for (int i = 0; i < 16; ++i) z16[i] = 0.f;
  f32x16 os[3];
#pragma unroll
  for (int i = 0; i < 3; ++i) os[i] = z16;

#define STAGE_K(KT)                                                        \
  {                                                                        \
    _Pragma("unroll") for (int i = 0; i < 6; ++i) {                        \
      int cid = i * 4 + w, sc = cid * 64 + lane;                           \
      int row = sc / 24, pc = sc % 24;                                     \
      int gc = (pc & ~7) | ((pc ^ row) & 7);                               \
      gll16(Kg + ((size_t)(KT) * 64 + row) * CC + gc * 8, sm + cid * 512); \
    }                                                                      \
  }
#define STAGE_V(KT)                                                        \
  {                                                                        \
    _Pragma("unroll") for (int i = 0; i < 6; ++i) {                        \
      int cid = i * 4 + w, sc = cid * 64 + lane;                           \
      int d = sc >> 3, pc = sc & 7, gc = (pc ^ d) & 7;                     \
      gll16(Vg + (size_t)d * NN + (KT) * 64 + gc * 8,                      \
            sm + 12288 + cid * 512);                                       \
    }                                                                      \
  }

  uint32_t pA[4][4];  // 4 A-frags (k-blocks of 16), full 64-k coverage
  // S(kt) -> blended bf16 A-frags, BOTH 32-k halves
#define S_BLEND()                                                           \
  {                                                                         \
    _Pragma("unroll") for (int kblk = 0; kblk < 2; ++kblk) {                \
      f32x16 sA = z16;                                                      \
      __builtin_amdgcn_s_setprio(1);                                        \
      _Pragma("unroll") for (int ks = 0; ks < 12; ++ks) {                   \
        bf16x8 kf =                                                         \
            *(const bf16x8*)&sm[swzK(kblk * 32 + l31, ks * 16 + hi * 8)];   \
        sA = __builtin_amdgcn_mfma_f32_32x32x16_bf16(kf, qf[ks], sA, 0, 0, 0); \
      }                                                                     \
      __builtin_amdgcn_s_setprio(0);                                        \
      uint32_t W[8];                                                        \
      _Pragma("unroll") for (int g = 0; g < 4; ++g) {                       \
        float sv0 = sA[4 * g + 0], sv1 = sA[4 * g + 1];                     \
        float sv2 = sA[4 * g + 2], sv3 = sA[4 * g + 3];                     \
        float p0 = cl1 * __expf(fminf(sv0, 60.f)) +                         \
                   c2f * ((sv0 > 0.f) ? sv0 * sv0 : 0.f);                   \
        float p1 = cl1 * __expf(fminf(sv1, 60.f)) +                         \
                   c2f * ((sv1 > 0.f) ? sv1 * sv1 : 0.f);                   \
        float p2 = cl1 * __expf(fminf(sv2, 60.f)) +                         \
                   c2f * ((sv2 > 0.f) ? sv2 * sv2 : 0.f);                   \
        float p3 = cl1 * __expf(fminf(sv3, 60.f)) +                         \
                   c2f * ((sv3 > 0.f) ? sv3 * sv3 : 0.f);                   \
        W[2 * g] = ((uint32_t)bf16bits(p1) << 16) | bf16bits(p0);           \
        W[2 * g + 1] = ((uint32_t)bf16bits(p3) << 16) | bf16bits(p2);       \
      }                                                                     \
      uint32_t X[8];                                                        \
      _Pragma("unroll") for (int jj = 0; jj < 8; ++jj)                      \
          X[jj] = __shfl_xor(W[jj], 32);                                    \
      pA[2 * kblk][0] = hi ? X[2] : W[0];                                   \
      pA[2 * kblk][1] = hi ? X[3] : W[1];                                   \
      pA[2 * kblk][2] = hi ? W[2] : X[0];                                   \
      pA[2 * kblk][3] = hi ? W[3] : X[1];                                   \
      pA[2 * kblk + 1][0] = hi ? X[6] : W[4];                               \
      pA[2 * kblk + 1][1] = hi ? X[7] : W[5];                               \
      pA[2 * kblk + 1][2] = hi ? W[6] : X[4];                               \
      pA[2 * kblk + 1][3] = hi ? W[7] : X[5];                               \
    }                                                                       \
  }

  // ---- prologue: K(0)+V(0) in flight; S(0) -> pA; issue K(1) ----
  STAGE_K(0);
  STAGE_V(0);
  asm volatile("s_waitcnt vmcnt(6)\ns_barrier" ::: "memory");  // K(0) landed
  S_BLEND();
  asm volatile("s_waitcnt lgkmcnt(0)\ns_barrier" ::: "memory"); // S reads done
  STAGE_K(1);

  for (int kt = 0; kt < 36; ++kt) {
    // A: V(kt) landed (6 newer K glls stay in flight)
    if (kt == 35)
      asm volatile("s_waitcnt vmcnt(0) lgkmcnt(0)\ns_barrier" ::: "memory");
    else
      asm volatile("s_waitcnt vmcnt(6) lgkmcnt(0)\ns_barrier" ::: "memory");

    // ---- PV(kt): os += P(kt) @ V(kt), full 64-k sum ----
    const u16* vl = sm + 12288;
    __builtin_amdgcn_s_setprio(1);
#pragma unroll
    for (int dt = 0; dt < 3; ++dt) {
      int d = ch * 96 + dt * 32 + l31;
#pragma unroll
      for (int kk = 0; kk < 4; ++kk) {
        bf16x8 vf = *(const bf16x8*)&vl[swz64(d, kk * 16 + hi * 8)];
        os[dt] = __builtin_amdgcn_mfma_f32_32x32x16_bf16(
            *(const bf16x8*)pA[kk], vf, os[dt], 0, 0, 0);
      }
    }
    __builtin_amdgcn_s_setprio(0);

    if (kt < 35) {
      // BC: PV reads done; K(kt+1) landed (only outstanding glls)
      asm volatile("s_waitcnt vmcnt(0) lgkmcnt(0)\ns_barrier" ::: "memory");
      STAGE_V(kt + 1);           // flies under S(kt+1) + next A
      S_BLEND();                 // S(kt+1) -> pA (P for next PV)
      // D: S reads done -> K region free
      asm volatile("s_waitcnt lgkmcnt(0)\ns_barrier" ::: "memory");
      if (kt + 2 < 36) STAGE_K(kt + 2);  // flies under PV(kt+1)
    }
  }

  // ---- epilogue: transpose via LDS overlay, residual add, coalesced store ----
  __syncthreads();
#pragma unroll
  for (int dt = 0; dt < 3; ++dt) {
    int d = ch * 96 + dt * 32 + l31;
#pragma unroll
    for (int r = 0; r < 16; ++r) {
      int m = (r & 3) + 8 * (r >> 2) + 4 * hi;
      int q = qh * 32 + m;
      olds[d * 64 + ((q & ~31) | ((q ^ d) & 31))] = os[dt][r];
    }
  }
  __syncthreads();
  const float* xb = x + (size_t)b * CC * NN + qt * 64;
  float* ob = out + (size_t)b * CC * NN + qt * 64;
#pragma unroll
  for (int i = 0; i < 48; ++i) {
    int idx = i * 256 + t;
    int c = idx >> 6, nn = idx & 63;
    float v = olds[c * 64 + ((nn & ~31) | ((nn ^ c) & 31))];
    ob[(size_t)c * NN + nn] = v + xb[(size_t)c * NN + nn];
  }
#undef STAGE_K
#undef STAGE_V
#undef S_BLEND
}

// ---------------------------------------------------------------------------
extern "C" void kernel_launch(void* const* d_in, const int* in_sizes, int n_in,
                              void* d_out, int out_size, void* d_ws, size_t ws_size,
                              hipStream_t stream) {
  (void)in_sizes; (void)n_in; (void)out_size; (void)ws_size;
  const float* x   = (const float*)d_in[0];
  const float* lnw = (const float*)d_in[1];
  const float* lnb = (const float*)d_in[2];
  const float* Wq  = (const float*)d_in[3];
  const float* Wk  = (const float*)d_in[4];
  const float* Wv  = (const float*)d_in[5];
  const float* w1  = (const float*)d_in[6];
  const float* w2  = (const float*)d_in[7];
  float* out = (float*)d_out;

  u16* xn = (u16*)d_ws;
  size_t per = (size_t)NBATCH * NN * CC;
  u16* qb  = xn + per;
  u16* kb  = qb + per;
  u16* vtb = kb + per;
  // lsum reuses the xn region (xn is dead after qkv_gemm; 147KB << 14MB)
  float* lsum_g = (float*)d_ws;

  ln_kernel<<<dim3(36, 16), 256, 0, stream>>>(x, lnw, lnb, xn);
  qkv_gemm<<<dim3(576, 3, 3), 256, 0, stream>>>(xn, Wq, Wk, Wv, qb, kb, vtb);
  attn_lsum<<<dim3(576), 256, 0, stream>>>(qb, kb, lsum_g);
  attn_pv<<<dim3(576), 256, 0, stream>>>(qb, kb, vtb, lsum_g, w1, w2, x, out);
}

// Round 7
// 295.333 us; speedup vs baseline: 1.8703x; 1.1709x over previous
//
#include <hip/hip_runtime.h>

#define NN 2304
#define CC 192
#define NBATCH 16

typedef unsigned short u16;
typedef __bf16 bf16x8 __attribute__((ext_vector_type(8)));
typedef float f32x4 __attribute__((ext_vector_type(4)));
typedef float f32x16 __attribute__((ext_vector_type(16)));

__device__ __forceinline__ u16 bf16bits(float f) {
  union { float f; unsigned u; } v;
  v.f = f;
  unsigned r = v.u + 0x7FFFu + ((v.u >> 16) & 1u);
  return (u16)(r >> 16);
}

// pack two f32 -> u32 of 2 bf16 (RNE), single HW instr
__device__ __forceinline__ uint32_t cvtpk(float lo, float hi) {
  uint32_t d;
  asm("v_cvt_pk_bf16_f32 %0, %1, %2" : "=v"(d) : "v"(lo), "v"(hi));
  return d;
}

// XOR-swizzled LDS element index for a [rows][192] bf16 tile (row stride 192).
__device__ __forceinline__ int swzK(int row, int col) {
  int ch = col >> 3;
  int phys = (ch & ~7) | ((ch ^ row) & 7);
  return row * 192 + (phys << 3) + (col & 7);
}
// Same for [rows][64] bf16 tiles (8 chunks per row).
__device__ __forceinline__ int swz64(int row, int col) {
  int ch = (col >> 3) ^ row;
  return (row << 6) | ((ch & 7) << 3) | (col & 7);
}

// direct global->LDS 16B DMA; dest = wave-uniform base + lane*16
__device__ __forceinline__ void gll16(const u16* g, u16* l) {
  __builtin_amdgcn_global_load_lds(
      (const __attribute__((address_space(1))) u16*)g,
      (__attribute__((address_space(3))) u16*)l, 16, 0, 0);
}

// ---------------------------------------------------------------------------
// Kernel 1: LayerNorm over C, x[b,c,n] (fp32) -> xn[(b*N+n), c] (bf16)
// ---------------------------------------------------------------------------
__global__ __launch_bounds__(256) void ln_kernel(
    const float* __restrict__ x, const float* __restrict__ lnw,
    const float* __restrict__ lnb, u16* __restrict__ xn) {
  __shared__ float xt[192 * 65];
  __shared__ float psum[4][64], psq[4][64];
  __shared__ float mu_s[64], rs_s[64];
  __shared__ float lw_s[192], lb_s[192];
  int t = threadIdx.x;
  int b = blockIdx.y, n0 = blockIdx.x * 64;
  const float* xb = x + (size_t)b * CC * NN;
  if (t < 192) { lw_s[t] = lnw[t]; lb_s[t] = lnb[t]; }
#pragma unroll
  for (int i = 0; i < 48; ++i) {
    int idx = i * 256 + t;
    int c = idx >> 6, n = idx & 63;
    xt[c * 65 + n] = xb[(size_t)c * NN + n0 + n];
  }
  __syncthreads();
  {
    int n = t & 63, part = t >> 6;
    float s = 0.f, s2 = 0.f;
#pragma unroll
    for (int c = part * 48; c < part * 48 + 48; ++c) {
      float v = xt[c * 65 + n];
      s += v; s2 += v * v;
    }
    psum[part][n] = s; psq[part][n] = s2;
  }
  __syncthreads();
  if (t < 64) {
    float s = psum[0][t] + psum[1][t] + psum[2][t] + psum[3][t];
    float s2 = psq[0][t] + psq[1][t] + psq[2][t] + psq[3][t];
    float mu = s * (1.0f / 192.0f);
    float var = s2 * (1.0f / 192.0f) - mu * mu;
    mu_s[t] = mu;
    rs_s[t] = rsqrtf(var + 1e-5f);
  }
  __syncthreads();
#pragma unroll
  for (int i = 0; i < 12; ++i) {
    int u = i * 256 + t;
    int n = u / 48, cq = (u % 48) * 4;
    float mu = mu_s[n], rs = rs_s[n];
    float v0 = (xt[(cq + 0) * 65 + n] - mu) * rs * lw_s[cq + 0] + lb_s[cq + 0];
    float v1 = (xt[(cq + 1) * 65 + n] - mu) * rs * lw_s[cq + 1] + lb_s[cq + 1];
    float v2 = (xt[(cq + 2) * 65 + n] - mu) * rs * lw_s[cq + 2] + lb_s[cq + 2];
    float v3 = (xt[(cq + 3) * 65 + n] - mu) * rs * lw_s[cq + 3] + lb_s[cq + 3];
    uint2 o;
    o.x = cvtpk(v0, v1);
    o.y = cvtpk(v2, v3);
    *(uint2*)&xn[((size_t)(b * NN + n0 + n)) * CC + cq] = o;
  }
}

// ---------------------------------------------------------------------------
// Kernel 2: QKV projections. y = xn @ W^T. 64x64 tiles, K=192.
// z==2 (V) writes transposed: vt[b][d][n].
// ---------------------------------------------------------------------------
__global__ __launch_bounds__(256, 3) void qkv_gemm(
    const u16* __restrict__ xn, const float* __restrict__ Wq,
    const float* __restrict__ Wk, const float* __restrict__ Wv,
    u16* __restrict__ qb, u16* __restrict__ kb, u16* __restrict__ vtb) {
  __shared__ u16 xs[12288];
  __shared__ u16 wsm[12288];
  int t = threadIdx.x, w = t >> 6, lane = t & 63, l15 = lane & 15, qd = lane >> 4;
  int m0 = blockIdx.x * 64, n0 = blockIdx.y * 64, z = blockIdx.z;
  const float* W = (z == 0) ? Wq : (z == 1 ? Wk : Wv);
#pragma unroll
  for (int i = 0; i < 6; ++i) {
    int ch = i * 256 + t;
    int row = ch / 24, cin = (ch % 24) * 8;
    *(uint4*)&xs[swzK(row, cin)] = *(const uint4*)&xn[(size_t)(m0 + row) * 192 + cin];
  }
#pragma unroll
  for (int i = 0; i < 6; ++i) {
    int ch = i * 256 + t;
    int row = ch / 24, cin = (ch % 24) * 8;
    const float* src = &W[(size_t)(n0 + row) * 192 + cin];
    float4 f0 = *(const float4*)src;
    float4 f1 = *(const float4*)(src + 4);
    uint4 o;
    o.x = cvtpk(f0.x, f0.y);
    o.y = cvtpk(f0.z, f0.w);
    o.z = cvtpk(f1.x, f1.y);
    o.w = cvtpk(f1.z, f1.w);
    *(uint4*)&wsm[swzK(row, cin)] = o;
  }
  __syncthreads();
  bf16x8 a[6];
#pragma unroll
  for (int kk = 0; kk < 6; ++kk)
    a[kk] = *(const bf16x8*)&xs[swzK(w * 16 + l15, kk * 32 + qd * 8)];
  const f32x4 fz = {0.f, 0.f, 0.f, 0.f};
  f32x4 acc[4];
#pragma unroll
  for (int ct = 0; ct < 4; ++ct) {
    acc[ct] = fz;
#pragma unroll
    for (int kk = 0; kk < 6; ++kk) {
      bf16x8 bfr = *(const bf16x8*)&wsm[swzK(ct * 16 + l15, kk * 32 + qd * 8)];
      acc[ct] = __builtin_amdgcn_mfma_f32_16x16x32_bf16(a[kk], bfr, acc[ct], 0, 0, 0);
    }
  }
  if (z < 2) {
    u16* outp = (z == 0) ? qb : kb;
#pragma unroll
    for (int ct = 0; ct < 4; ++ct)
#pragma unroll
      for (int r = 0; r < 4; ++r) {
        int m = m0 + w * 16 + qd * 4 + r;
        outp[(size_t)m * 192 + n0 + ct * 16 + l15] = bf16bits(acc[ct][r]);
      }
  } else {
    __syncthreads();
#pragma unroll
    for (int ct = 0; ct < 4; ++ct)
#pragma unroll
      for (int r = 0; r < 4; ++r)
        xs[swz64(ct * 16 + l15, w * 16 + qd * 4 + r)] = bf16bits(acc[ct][r]);
    __syncthreads();
    int b = blockIdx.x / 36, nb = (blockIdx.x % 36) * 64;
#pragma unroll
    for (int i = 0; i < 16; ++i) {
      int idx = i * 256 + t;
      int d = idx >> 6, nn = idx & 63;
      vtb[(size_t)b * 192 * NN + (size_t)(n0 + d) * NN + nb + nn] = xs[swz64(d, nn)];
    }
  }
}

// ---------------------------------------------------------------------------
// Kernel 3a: pass 1 — softmax denominators. S^T = K·Q^T (swapped operands ->
// lane-local q cols), lsum[q] = sum_k exp(min(S,60)).
// ---------------------------------------------------------------------------
__global__ __launch_bounds__(256, 3) void attn_lsum(
    const u16* __restrict__ qb, const u16* __restrict__ kb,
    float* __restrict__ lsum_g) {
  __shared__ u16 sm[24576];        // K dbuf: 2 x [64][192] bf16 (swzK)
  __shared__ float lp[2][2][32];   // [qh][ch][q]
  int t = threadIdx.x, w = t >> 6, lane = t & 63;
  int l31 = lane & 31, hi = lane >> 5;
  int qh = w >> 1, ch = w & 1;
  int bid = blockIdx.x;
  int xcd = bid & 7, j = bid >> 3;
  int b = xcd * 2 + (j >= 36 ? 1 : 0);
  int qt = (j >= 36) ? j - 36 : j;

  const u16* Kg = kb + (size_t)b * NN * CC;
  const u16* Qr = qb + ((size_t)b * NN + qt * 64 + qh * 32 + l31) * CC + hi * 8;
  bf16x8 qf[12];
#pragma unroll
  for (int ks = 0; ks < 12; ++ks) qf[ks] = *(const bf16x8*)(Qr + ks * 16);

  // stage K(0) -> buf0
#pragma unroll
  for (int i = 0; i < 6; ++i) {
    int cid = i * 4 + w, sc = cid * 64 + lane;
    int row = sc / 24, pc = sc % 24;
    int gc = (pc & ~7) | ((pc ^ row) & 7);
    gll16(Kg + (size_t)row * CC + gc * 8, sm + cid * 512);
  }

  f32x16 z16;
#pragma unroll
  for (int i = 0; i < 16; ++i) z16[i] = 0.f;
  float lsum = 0.f;

  for (int kt = 0; kt < 36; ++kt) {
    asm volatile("s_waitcnt vmcnt(0) lgkmcnt(0)\ns_barrier" ::: "memory");
    if (kt + 1 < 36) {
      u16* dst = sm + ((kt + 1) & 1) * 12288;
#pragma unroll
      for (int i = 0; i < 6; ++i) {
        int cid = i * 4 + w, sc = cid * 64 + lane;
        int row = sc / 24, pc = sc % 24;
        int gc = (pc & ~7) | ((pc ^ row) & 7);
        gll16(Kg + ((size_t)(kt + 1) * 64 + row) * CC + gc * 8, dst + cid * 512);
      }
    }
    const u16* kl = sm + (kt & 1) * 12288;
    f32x16 s0 = z16, s1 = z16;
    __builtin_amdgcn_s_setprio(1);
#pragma unroll
    for (int ks = 0; ks < 6; ++ks) {
      bf16x8 k0 = *(const bf16x8*)&kl[swzK(ch * 32 + l31, (2 * ks) * 16 + hi * 8)];
      bf16x8 k1 = *(const bf16x8*)&kl[swzK(ch * 32 + l31, (2 * ks + 1) * 16 + hi * 8)];
      s0 = __builtin_amdgcn_mfma_f32_32x32x16_bf16(k0, qf[2 * ks], s0, 0, 0, 0);
      s1 = __builtin_amdgcn_mfma_f32_32x32x16_bf16(k1, qf[2 * ks + 1], s1, 0, 0, 0);
    }
    __builtin_amdgcn_s_setprio(0);
#pragma unroll
    for (int r = 0; r < 16; ++r) {
      float s = s0[r] + s1[r];
      lsum += __expf(fminf(s, 60.f));
    }
  }
  lsum += __shfl_xor(lsum, 32);
  if (lane < 32) lp[qh][ch][l31] = lsum;
  __syncthreads();
  if (w == 0) {
    lsum_g[(size_t)b * NN + qt * 64 + lane] =
        lp[lane >> 5][0][lane & 31] + lp[lane >> 5][1][lane & 31];
  }
}

// ---------------------------------------------------------------------------
// Kernel 3b: pass 2 — blended single-accumulator PV.
// R6 post-mortem fix: kill the duplicated S work. Wave (qh,ch) computes S^T
// for k-rows ch*32..+31 ONLY (12 MFMA, 16 blends — both halved), packs its
// two P A-frags (cvt_pk_bf16 + shfl_xor(32)), keeps them in regs AND writes
// them to an 8KB LDS exchange buffer; PV reads the sibling wave's two frags
// back. Existing barriers already order write->read (D) and read->overwrite
// (BC). LDS 56KB, launch_bounds(256,2) -> no spill, 2 blocks/CU.
// ---------------------------------------------------------------------------
__global__ __launch_bounds__(256, 2) void attn_pv(
    const u16* __restrict__ qb, const u16* __restrict__ kb,
    const u16* __restrict__ vtb, const float* __restrict__ lsum_g,
    const float* __restrict__ w1p, const float* __restrict__ w2p,
    const float* __restrict__ x, float* __restrict__ out) {
  __shared__ u16 sm[28672];        // K [64][192] @0 | V^T @12288 | pex @24576 (8KB)
  float* olds = (float*)sm;        // epilogue overlay [192][64] f32 (48K)

  int t = threadIdx.x, w = t >> 6, lane = t & 63;
  int l31 = lane & 31, hi = lane >> 5;
  int qh = w >> 1, ch = w & 1;
  int bid = blockIdx.x;
  int xcd = bid & 7, j = bid >> 3;
  int b = xcd * 2 + (j >= 36 ? 1 : 0);
  int qt = (j >= 36) ? j - 36 : j;

  const u16* Kg = kb + (size_t)b * NN * CC;
  const u16* Vg = vtb + (size_t)b * CC * NN;
  const u16* Qr = qb + ((size_t)b * NN + qt * 64 + qh * 32 + l31) * CC + hi * 8;
  bf16x8 qf[12];
#pragma unroll
  for (int ks = 0; ks < 12; ++ks) qf[ks] = *(const bf16x8*)(Qr + ks * 16);

  float e1 = __expf(w1p[0]), e2 = __expf(w2p[0]);
  float den = e1 + e2;
  float c2f = e2 / den;
  float cl1 = (e1 / den) / lsum_g[(size_t)b * NN + qt * 64 + qh * 32 + l31];

  // P-frag exchange buffer: [qh*2+chOwner] regions of 2 frags x 64 lanes x 16B
  u16* pexW = sm + 24576 + (qh * 2 + ch) * 1024 + lane * 8;
  const u16* pexR = sm + 24576 + (qh * 2 + (1 - ch)) * 1024 + lane * 8;

  f32x16 z16;
#pragma unroll
  for (int i = 0; i < 16; ++i) z16[i] = 0.f;
  f32x16 os[3];
#pragma unroll
  for (int i = 0; i < 3; ++i) os[i] = z16;

#define STAGE_K(KT)                                                        \
  {                                                                        \
    _Pragma("unroll") for (int i = 0; i < 6; ++i) {                        \
      int cid = i * 4 + w, sc = cid * 64 + lane;                           \
      int row = sc / 24, pc = sc % 24;                                     \
      int gc = (pc & ~7) | ((pc ^ row) & 7);                               \
      gll16(Kg + ((size_t)(KT) * 64 + row) * CC + gc * 8, sm + cid * 512); \
    }                                                                      \
  }
#define STAGE_V(KT)                                                        \
  {                                                                        \
    _Pragma("unroll") for (int i = 0; i < 6; ++i) {                        \
      int cid = i * 4 + w, sc = cid * 64 + lane;                           \
      int d = sc >> 3, pc = sc & 7, gc = (pc ^ d) & 7;                     \
      gll16(Vg + (size_t)d * NN + (KT) * 64 + gc * 8,                      \
            sm + 12288 + cid * 512);                                       \
    }                                                                      \
  }

  alignas(16) uint32_t pOwn0[4], pOwn1[4];
  // S(kt) for own k-block only -> blend -> pack -> regs + pex
#define S_BLEND()                                                           \
  {                                                                         \
    f32x16 sA0 = z16, sA1 = z16;                                            \
    __builtin_amdgcn_s_setprio(1);                                          \
    _Pragma("unroll") for (int ks = 0; ks < 6; ++ks) {                      \
      bf16x8 k0 =                                                           \
          *(const bf16x8*)&sm[swzK(ch * 32 + l31, (2 * ks) * 16 + hi * 8)]; \
      bf16x8 k1 =                                                           \
          *(const bf16x8*)&sm[swzK(ch * 32 + l31, (2 * ks + 1) * 16 + hi * 8)]; \
      sA0 = __builtin_amdgcn_mfma_f32_32x32x16_bf16(k0, qf[2 * ks], sA0, 0, 0, 0); \
      sA1 = __builtin_amdgcn_mfma_f32_32x32x16_bf16(k1, qf[2 * ks + 1], sA1, 0, 0, 0); \
    }                                                                       \
    __builtin_amdgcn_s_setprio(0);                                          \
    uint32_t W[8];                                                          \
    _Pragma("unroll") for (int g = 0; g < 4; ++g) {                         \
      float sv0 = sA0[4 * g + 0] + sA1[4 * g + 0];                          \
      float sv1 = sA0[4 * g + 1] + sA1[4 * g + 1];                          \
      float sv2 = sA0[4 * g + 2] + sA1[4 * g + 2];                          \
      float sv3 = sA0[4 * g + 3] + sA1[4 * g + 3];                          \
      float r0 = fmaxf(sv0, 0.f), r1 = fmaxf(sv1, 0.f);                     \
      float r2 = fmaxf(sv2, 0.f), r3 = fmaxf(sv3, 0.f);                     \
      float p0 = cl1 * __expf(fminf(sv0, 60.f)) + c2f * r0 * r0;            \
      float p1 = cl1 * __expf(fminf(sv1, 60.f)) + c2f * r1 * r1;            \
      float p2 = cl1 * __expf(fminf(sv2, 60.f)) + c2f * r2 * r2;            \
      float p3 = cl1 * __expf(fminf(sv3, 60.f)) + c2f * r3 * r3;            \
      W[2 * g] = cvtpk(p0, p1);                                             \
      W[2 * g + 1] = cvtpk(p2, p3);                                         \
    }                                                                       \
    uint32_t X[8];                                                          \
    _Pragma("unroll") for (int jj = 0; jj < 8; ++jj)                        \
        X[jj] = __shfl_xor(W[jj], 32);                                      \
    pOwn0[0] = hi ? X[2] : W[0]; pOwn0[1] = hi ? X[3] : W[1];               \
    pOwn0[2] = hi ? W[2] : X[0]; pOwn0[3] = hi ? W[3] : X[1];               \
    pOwn1[0] = hi ? X[6] : W[4]; pOwn1[1] = hi ? X[7] : W[5];               \
    pOwn1[2] = hi ? W[6] : X[4]; pOwn1[3] = hi ? W[7] : X[5];               \
    *(uint4*)pexW = *(uint4*)pOwn0;                                         \
    *(uint4*)(pexW + 512) = *(uint4*)pOwn1;                                 \
  }

  // ---- prologue: K(0)+V(0) in flight; S(0) -> pOwn/pex; issue K(1) ----
  STAGE_K(0);
  STAGE_V(0);
  asm volatile("s_waitcnt vmcnt(6)\ns_barrier" ::: "memory");  // K(0) landed
  S_BLEND();
  asm volatile("s_waitcnt lgkmcnt(0)\ns_barrier" ::: "memory"); // S reads + pex writes done
  STAGE_K(1);

  for (int kt = 0; kt < 36; ++kt) {
    // A: V(kt) landed (6 newer K glls stay in flight)
    if (kt == 35)
      asm volatile("s_waitcnt vmcnt(0) lgkmcnt(0)\ns_barrier" ::: "memory");
    else
      asm volatile("s_waitcnt vmcnt(6) lgkmcnt(0)\ns_barrier" ::: "memory");

    // ---- PV(kt): os += P(kt) @ V(kt); own frags from regs, sibling from pex
    const u16* vl = sm + 12288;
    uint4 pb0 = *(const uint4*)pexR;
    uint4 pb1 = *(const uint4*)(pexR + 512);
    __builtin_amdgcn_s_setprio(1);
#pragma unroll
    for (int dt = 0; dt < 3; ++dt) {
      int d = ch * 96 + dt * 32 + l31;
      bf16x8 vo0 = *(const bf16x8*)&vl[swz64(d, (ch * 2 + 0) * 16 + hi * 8)];
      bf16x8 vo1 = *(const bf16x8*)&vl[swz64(d, (ch * 2 + 1) * 16 + hi * 8)];
      bf16x8 vs0 = *(const bf16x8*)&vl[swz64(d, ((1 - ch) * 2 + 0) * 16 + hi * 8)];
      bf16x8 vs1 = *(const bf16x8*)&vl[swz64(d, ((1 - ch) * 2 + 1) * 16 + hi * 8)];
      os[dt] = __builtin_amdgcn_mfma_f32_32x32x16_bf16(
          *(const bf16x8*)pOwn0, vo0, os[dt], 0, 0, 0);
      os[dt] = __builtin_amdgcn_mfma_f32_32x32x16_bf16(
          *(const bf16x8*)pOwn1, vo1, os[dt], 0, 0, 0);
      os[dt] = __builtin_amdgcn_mfma_f32_32x32x16_bf16(
          *(const bf16x8*)&pb0, vs0, os[dt], 0, 0, 0);
      os[dt] = __builtin_amdgcn_mfma_f32_32x32x16_bf16(
          *(const bf16x8*)&pb1, vs1, os[dt], 0, 0, 0);
    }
    __builtin_amdgcn_s_setprio(0);

    if (kt < 35) {
      // BC: PV reads (incl pex) done; K(kt+1) landed (only outstanding glls)
      asm volatile("s_waitcnt vmcnt(0) lgkmcnt(0)\ns_barrier" ::: "memory");
      STAGE_V(kt + 1);           // flies under S(kt+1) + next A
      S_BLEND();                 // S(kt+1) -> pOwn/pex (P for next PV)
      // D: S reads done + pex writes drained -> K region free, pex published
      asm volatile("s_waitcnt lgkmcnt(0)\ns_barrier" ::: "memory");
      if (kt + 2 < 36) STAGE_K(kt + 2);  // flies under PV(kt+1)
    }
  }

  // ---- epilogue: transpose via LDS overlay, residual add, coalesced store ----
  __syncthreads();
#pragma unroll
  for (int dt = 0; dt < 3; ++dt) {
    int d = ch * 96 + dt * 32 + l31;
#pragma unroll
    for (int r = 0; r < 16; ++r) {
      int m = (r & 3) + 8 * (r >> 2) + 4 * hi;
      int q = qh * 32 + m;
      olds[d * 64 + ((q & ~31) | ((q ^ d) & 31))] = os[dt][r];
    }
  }
  __syncthreads();
  const float* xb = x + (size_t)b * CC * NN + qt * 64;
  float* ob = out + (size_t)b * CC * NN + qt * 64;
#pragma unroll
  for (int i = 0; i < 48; ++i) {
    int idx = i * 256 + t;
    int c = idx >> 6, nn = idx & 63;
    float v = olds[c * 64 + ((nn & ~31) | ((nn ^ c) & 31))];
    ob[(size_t)c * NN + nn] = v + xb[(size_t)c * NN + nn];
  }
#undef STAGE_K
#undef STAGE_V
#undef S_BLEND
}

// ---------------------------------------------------------------------------
extern "C" void kernel_launch(void* const* d_in, const int* in_sizes, int n_in,
                              void* d_out, int out_size, void* d_ws, size_t ws_size,
                              hipStream_t stream) {
  (void)in_sizes; (void)n_in; (void)out_size; (void)ws_size;
  const float* x   = (const float*)d_in[0];
  const float* lnw = (const float*)d_in[1];
  const float* lnb = (const float*)d_in[2];
  const float* Wq  = (const float*)d_in[3];
  const float* Wk  = (const float*)d_in[4];
  const float* Wv  = (const float*)d_in[5];
  const float* w1  = (const float*)d_in[6];
  const float* w2  = (const float*)d_in[7];
  float* out = (float*)d_out;

  u16* xn = (u16*)d_ws;
  size_t per = (size_t)NBATCH * NN * CC;
  u16* qb  = xn + per;
  u16* kb  = qb + per;
  u16* vtb = kb + per;
  // lsum reuses the xn region (xn is dead after qkv_gemm; 147KB << 14MB)
  float* lsum_g = (float*)d_ws;

  ln_kernel<<<dim3(36, 16), 256, 0, stream>>>(x, lnw, lnb, xn);
  qkv_gemm<<<dim3(576, 3, 3), 256, 0, stream>>>(xn, Wq, Wk, Wv, qb, kb, vtb);
  attn_lsum<<<dim3(576), 256, 0, stream>>>(qb, kb, lsum_g);
  attn_pv<<<dim3(576), 256, 0, stream>>>(qb, kb, vtb, lsum_g, w1, w2, x, out);
}

// Round 8
// 283.123 us; speedup vs baseline: 1.9510x; 1.0431x over previous
//
#include <hip/hip_runtime.h>

#define NN 2304
#define CC 192
#define NBATCH 16

typedef unsigned short u16;
typedef __bf16 bf16x8 __attribute__((ext_vector_type(8)));
typedef float f32x4 __attribute__((ext_vector_type(4)));
typedef float f32x16 __attribute__((ext_vector_type(16)));

__device__ __forceinline__ u16 bf16bits(float f) {
  union { float f; unsigned u; } v;
  v.f = f;
  unsigned r = v.u + 0x7FFFu + ((v.u >> 16) & 1u);
  return (u16)(r >> 16);
}

// pack two f32 -> u32 of 2 bf16 (RNE), single HW instr
__device__ __forceinline__ uint32_t cvtpk(float lo, float hi) {
  uint32_t d;
  asm("v_cvt_pk_bf16_f32 %0, %1, %2" : "=v"(d) : "v"(lo), "v"(hi));
  return d;
}

// XOR-swizzled LDS element index for a [rows][192] bf16 tile (row stride 192).
__device__ __forceinline__ int swzK(int row, int col) {
  int ch = col >> 3;
  int phys = (ch & ~7) | ((ch ^ row) & 7);
  return row * 192 + (phys << 3) + (col & 7);
}
// Same for [rows][64] bf16 tiles (8 chunks per row).
__device__ __forceinline__ int swz64(int row, int col) {
  int ch = (col >> 3) ^ row;
  return (row << 6) | ((ch & 7) << 3) | (col & 7);
}

// direct global->LDS 16B DMA; dest = wave-uniform base + lane*16
__device__ __forceinline__ void gll16(const u16* g, u16* l) {
  __builtin_amdgcn_global_load_lds(
      (const __attribute__((address_space(1))) u16*)g,
      (__attribute__((address_space(3))) u16*)l, 16, 0, 0);
}

// ---------------------------------------------------------------------------
// Kernel 1: LayerNorm over C, x[b,c,n] (fp32) -> xn[(b*N+n), c] (bf16)
// ---------------------------------------------------------------------------
__global__ __launch_bounds__(256) void ln_kernel(
    const float* __restrict__ x, const float* __restrict__ lnw,
    const float* __restrict__ lnb, u16* __restrict__ xn) {
  __shared__ float xt[192 * 65];
  __shared__ float psum[4][64], psq[4][64];
  __shared__ float mu_s[64], rs_s[64];
  __shared__ float lw_s[192], lb_s[192];
  int t = threadIdx.x;
  int b = blockIdx.y, n0 = blockIdx.x * 64;
  const float* xb = x + (size_t)b * CC * NN;
  if (t < 192) { lw_s[t] = lnw[t]; lb_s[t] = lnb[t]; }
#pragma unroll
  for (int i = 0; i < 48; ++i) {
    int idx = i * 256 + t;
    int c = idx >> 6, n = idx & 63;
    xt[c * 65 + n] = xb[(size_t)c * NN + n0 + n];
  }
  __syncthreads();
  {
    int n = t & 63, part = t >> 6;
    float s = 0.f, s2 = 0.f;
#pragma unroll
    for (int c = part * 48; c < part * 48 + 48; ++c) {
      float v = xt[c * 65 + n];
      s += v; s2 += v * v;
    }
    psum[part][n] = s; psq[part][n] = s2;
  }
  __syncthreads();
  if (t < 64) {
    float s = psum[0][t] + psum[1][t] + psum[2][t] + psum[3][t];
    float s2 = psq[0][t] + psq[1][t] + psq[2][t] + psq[3][t];
    float mu = s * (1.0f / 192.0f);
    float var = s2 * (1.0f / 192.0f) - mu * mu;
    mu_s[t] = mu;
    rs_s[t] = rsqrtf(var + 1e-5f);
  }
  __syncthreads();
#pragma unroll
  for (int i = 0; i < 12; ++i) {
    int u = i * 256 + t;
    int n = u / 48, cq = (u % 48) * 4;
    float mu = mu_s[n], rs = rs_s[n];
    float v0 = (xt[(cq + 0) * 65 + n] - mu) * rs * lw_s[cq + 0] + lb_s[cq + 0];
    float v1 = (xt[(cq + 1) * 65 + n] - mu) * rs * lw_s[cq + 1] + lb_s[cq + 1];
    float v2 = (xt[(cq + 2) * 65 + n] - mu) * rs * lw_s[cq + 2] + lb_s[cq + 2];
    float v3 = (xt[(cq + 3) * 65 + n] - mu) * rs * lw_s[cq + 3] + lb_s[cq + 3];
    uint2 o;
    o.x = cvtpk(v0, v1);
    o.y = cvtpk(v2, v3);
    *(uint2*)&xn[((size_t)(b * NN + n0 + n)) * CC + cq] = o;
  }
}

// ---------------------------------------------------------------------------
// Kernel 2: QKV projections. y = xn @ W^T. 64x64 tiles, K=192.
// z==2 (V) writes transposed: vt[b][d][n].
// ---------------------------------------------------------------------------
__global__ __launch_bounds__(256, 3) void qkv_gemm(
    const u16* __restrict__ xn, const float* __restrict__ Wq,
    const float* __restrict__ Wk, const float* __restrict__ Wv,
    u16* __restrict__ qb, u16* __restrict__ kb, u16* __restrict__ vtb) {
  __shared__ u16 xs[12288];
  __shared__ u16 wsm[12288];
  int t = threadIdx.x, w = t >> 6, lane = t & 63, l15 = lane & 15, qd = lane >> 4;
  int m0 = blockIdx.x * 64, n0 = blockIdx.y * 64, z = blockIdx.z;
  const float* W = (z == 0) ? Wq : (z == 1 ? Wk : Wv);
#pragma unroll
  for (int i = 0; i < 6; ++i) {
    int ch = i * 256 + t;
    int row = ch / 24, cin = (ch % 24) * 8;
    *(uint4*)&xs[swzK(row, cin)] = *(const uint4*)&xn[(size_t)(m0 + row) * 192 + cin];
  }
#pragma unroll
  for (int i = 0; i < 6; ++i) {
    int ch = i * 256 + t;
    int row = ch / 24, cin = (ch % 24) * 8;
    const float* src = &W[(size_t)(n0 + row) * 192 + cin];
    float4 f0 = *(const float4*)src;
    float4 f1 = *(const float4*)(src + 4);
    uint4 o;
    o.x = cvtpk(f0.x, f0.y);
    o.y = cvtpk(f0.z, f0.w);
    o.z = cvtpk(f1.x, f1.y);
    o.w = cvtpk(f1.z, f1.w);
    *(uint4*)&wsm[swzK(row, cin)] = o;
  }
  __syncthreads();
  bf16x8 a[6];
#pragma unroll
  for (int kk = 0; kk < 6; ++kk)
    a[kk] = *(const bf16x8*)&xs[swzK(w * 16 + l15, kk * 32 + qd * 8)];
  const f32x4 fz = {0.f, 0.f, 0.f, 0.f};
  f32x4 acc[4];
#pragma unroll
  for (int ct = 0; ct < 4; ++ct) {
    acc[ct] = fz;
#pragma unroll
    for (int kk = 0; kk < 6; ++kk) {
      bf16x8 bfr = *(const bf16x8*)&wsm[swzK(ct * 16 + l15, kk * 32 + qd * 8)];
      acc[ct] = __builtin_amdgcn_mfma_f32_16x16x32_bf16(a[kk], bfr, acc[ct], 0, 0, 0);
    }
  }
  if (z < 2) {
    u16* outp = (z == 0) ? qb : kb;
#pragma unroll
    for (int ct = 0; ct < 4; ++ct)
#pragma unroll
      for (int r = 0; r < 4; ++r) {
        int m = m0 + w * 16 + qd * 4 + r;
        outp[(size_t)m * 192 + n0 + ct * 16 + l15] = bf16bits(acc[ct][r]);
      }
  } else {
    __syncthreads();
#pragma unroll
    for (int ct = 0; ct < 4; ++ct)
#pragma unroll
      for (int r = 0; r < 4; ++r)
        xs[swz64(ct * 16 + l15, w * 16 + qd * 4 + r)] = bf16bits(acc[ct][r]);
    __syncthreads();
    int b = blockIdx.x / 36, nb = (blockIdx.x % 36) * 64;
#pragma unroll
    for (int i = 0; i < 16; ++i) {
      int idx = i * 256 + t;
      int d = idx >> 6, nn = idx & 63;
      vtb[(size_t)b * 192 * NN + (size_t)(n0 + d) * NN + nb + nn] = xs[swz64(d, nn)];
    }
  }
}

// ---------------------------------------------------------------------------
// Kernel 3: SINGLE-PASS fused attention (lsum pass eliminated).
// Wave (qh,ch): S^T for own k-half (12 MFMA), dual P-sets packed in-register
// (exp + relu^2; 16 cvtpk + 16 shfl), both exchanged via 16KB pex; PV with
// dual accumulators os/orl (24 MFMA, V-frags shared); lane-local lsum.
// Epilogue: reduce lsum (shfl32 + LDS), blend os*(c1/l)+c2*orl, transpose,
// residual add, store. Pipeline/barriers identical to R7 (counted vmcnt).
// LDS 64KB, launch_bounds(256,2) -> ~220 regs, no spill, 2 blocks/CU.
// ---------------------------------------------------------------------------
__global__ __launch_bounds__(256, 2) void attn_fused(
    const u16* __restrict__ qb, const u16* __restrict__ kb,
    const u16* __restrict__ vtb, const float* __restrict__ w1p,
    const float* __restrict__ w2p, const float* __restrict__ x,
    float* __restrict__ out) {
  __shared__ u16 sm[32768];   // K@0 24KB | V^T@12288 24KB | pexS@24576 8KB | pexR@28672 8KB
  float* olds = (float*)sm;   // epilogue overlay [192][64] f32 (48KB, bytes 0..49151)
  float* lred = (float*)(sm + 24576);  // epilogue lsum exchange (bytes 49152+)

  int t = threadIdx.x, w = t >> 6, lane = t & 63;
  int l31 = lane & 31, hi = lane >> 5;
  int qh = w >> 1, ch = w & 1;
  int bid = blockIdx.x;
  int xcd = bid & 7, j = bid >> 3;
  int b = xcd * 2 + (j >= 36 ? 1 : 0);
  int qt = (j >= 36) ? j - 36 : j;

  const u16* Kg = kb + (size_t)b * NN * CC;
  const u16* Vg = vtb + (size_t)b * CC * NN;
  const u16* Qr = qb + ((size_t)b * NN + qt * 64 + qh * 32 + l31) * CC + hi * 8;
  bf16x8 qf[12];
#pragma unroll
  for (int ks = 0; ks < 12; ++ks) qf[ks] = *(const bf16x8*)(Qr + ks * 16);

  float e1 = __expf(w1p[0]), e2 = __expf(w2p[0]);
  float den = e1 + e2;
  float c1f = e1 / den, c2f = e2 / den;

  // P-frag exchange: per owner-wave region of 2 frags x 64 lanes x 16B (2KB)
  u16* pexSW = sm + 24576 + (qh * 2 + ch) * 1024 + lane * 8;
  const u16* pexSR = sm + 24576 + (qh * 2 + (1 - ch)) * 1024 + lane * 8;
  u16* pexRW = sm + 28672 + (qh * 2 + ch) * 1024 + lane * 8;
  const u16* pexRR = sm + 28672 + (qh * 2 + (1 - ch)) * 1024 + lane * 8;

  f32x16 z16;
#pragma unroll
  for (int i = 0; i < 16; ++i) z16[i] = 0.f;
  f32x16 os[3], orl[3];
#pragma unroll
  for (int i = 0; i < 3; ++i) { os[i] = z16; orl[i] = z16; }
  float lsum = 0.f;

#define STAGE_K(KT)                                                        \
  {                                                                        \
    _Pragma("unroll") for (int i = 0; i < 6; ++i) {                        \
      int cid = i * 4 + w, sc = cid * 64 + lane;                           \
      int row = sc / 24, pc = sc % 24;                                     \
      int gc = (pc & ~7) | ((pc ^ row) & 7);                               \
      gll16(Kg + ((size_t)(KT) * 64 + row) * CC + gc * 8, sm + cid * 512); \
    }                                                                      \
  }
#define STAGE_V(KT)                                                        \
  {                                                                        \
    _Pragma("unroll") for (int i = 0; i < 6; ++i) {                        \
      int cid = i * 4 + w, sc = cid * 64 + lane;                           \
      int d = sc >> 3, pc = sc & 7, gc = (pc ^ d) & 7;                     \
      gll16(Vg + (size_t)d * NN + (KT) * 64 + gc * 8,                      \
            sm + 12288 + cid * 512);                                       \
    }                                                                      \
  }

  alignas(16) uint32_t pS0[4], pS1[4], pR0[4], pR1[4];
  // S(kt) for own k-half -> exp & relu^2 packed to TWO A-frag sets; lsum accum
#define S_BLEND()                                                           \
  {                                                                         \
    f32x16 sA0 = z16, sA1 = z16;                                            \
    __builtin_amdgcn_s_setprio(1);                                          \
    _Pragma("unroll") for (int ks = 0; ks < 6; ++ks) {                      \
      bf16x8 k0 =                                                           \
          *(const bf16x8*)&sm[swzK(ch * 32 + l31, (2 * ks) * 16 + hi * 8)]; \
      bf16x8 k1 =                                                           \
          *(const bf16x8*)&sm[swzK(ch * 32 + l31, (2 * ks + 1) * 16 + hi * 8)]; \
      sA0 = __builtin_amdgcn_mfma_f32_32x32x16_bf16(k0, qf[2 * ks], sA0, 0, 0, 0); \
      sA1 = __builtin_amdgcn_mfma_f32_32x32x16_bf16(k1, qf[2 * ks + 1], sA1, 0, 0, 0); \
    }                                                                       \
    __builtin_amdgcn_s_setprio(0);                                          \
    uint32_t WS[8], WR[8];                                                  \
    _Pragma("unroll") for (int g = 0; g < 4; ++g) {                         \
      float sv0 = sA0[4 * g + 0] + sA1[4 * g + 0];                          \
      float sv1 = sA0[4 * g + 1] + sA1[4 * g + 1];                          \
      float sv2 = sA0[4 * g + 2] + sA1[4 * g + 2];                          \
      float sv3 = sA0[4 * g + 3] + sA1[4 * g + 3];                          \
      float e0 = __expf(fminf(sv0, 60.f));                                  \
      float e1v = __expf(fminf(sv1, 60.f));                                 \
      float e2v = __expf(fminf(sv2, 60.f));                                 \
      float e3 = __expf(fminf(sv3, 60.f));                                  \
      float r0 = fmaxf(sv0, 0.f), r1 = fmaxf(sv1, 0.f);                     \
      float r2 = fmaxf(sv2, 0.f), r3 = fmaxf(sv3, 0.f);                     \
      lsum += (e0 + e1v) + (e2v + e3);                                      \
      WS[2 * g] = cvtpk(e0, e1v);                                           \
      WS[2 * g + 1] = cvtpk(e2v, e3);                                       \
      WR[2 * g] = cvtpk(r0 * r0, r1 * r1);                                  \
      WR[2 * g + 1] = cvtpk(r2 * r2, r3 * r3);                              \
    }                                                                       \
    uint32_t XS[8], XR[8];                                                  \
    _Pragma("unroll") for (int jj = 0; jj < 8; ++jj) {                      \
      XS[jj] = __shfl_xor(WS[jj], 32);                                      \
      XR[jj] = __shfl_xor(WR[jj], 32);                                      \
    }                                                                       \
    pS0[0] = hi ? XS[2] : WS[0]; pS0[1] = hi ? XS[3] : WS[1];               \
    pS0[2] = hi ? WS[2] : XS[0]; pS0[3] = hi ? WS[3] : XS[1];               \
    pS1[0] = hi ? XS[6] : WS[4]; pS1[1] = hi ? XS[7] : WS[5];               \
    pS1[2] = hi ? WS[6] : XS[4]; pS1[3] = hi ? WS[7] : XS[5];               \
    pR0[0] = hi ? XR[2] : WR[0]; pR0[1] = hi ? XR[3] : WR[1];               \
    pR0[2] = hi ? WR[2] : XR[0]; pR0[3] = hi ? WR[3] : XR[1];               \
    pR1[0] = hi ? XR[6] : WR[4]; pR1[1] = hi ? XR[7] : WR[5];               \
    pR1[2] = hi ? WR[6] : XR[4]; pR1[3] = hi ? WR[7] : XR[5];               \
    *(uint4*)pexSW = *(uint4*)pS0;                                          \
    *(uint4*)(pexSW + 512) = *(uint4*)pS1;                                  \
    *(uint4*)pexRW = *(uint4*)pR0;                                          \
    *(uint4*)(pexRW + 512) = *(uint4*)pR1;                                  \
  }

  // ---- prologue: K(0)+V(0) in flight; S(0) -> frags; issue K(1) ----
  STAGE_K(0);
  STAGE_V(0);
  asm volatile("s_waitcnt vmcnt(6)\ns_barrier" ::: "memory");   // K(0) landed
  S_BLEND();
  asm volatile("s_waitcnt lgkmcnt(0)\ns_barrier" ::: "memory"); // S reads + pex pub
  STAGE_K(1);

  for (int kt = 0; kt < 36; ++kt) {
    // A: V(kt) landed (6 newer K glls stay in flight)
    if (kt == 35)
      asm volatile("s_waitcnt vmcnt(0) lgkmcnt(0)\ns_barrier" ::: "memory");
    else
      asm volatile("s_waitcnt vmcnt(6) lgkmcnt(0)\ns_barrier" ::: "memory");

    // ---- PV(kt): os/orl += P @ V; own frags regs, sibling via pex ----
    const u16* vl = sm + 12288;
    uint4 sS0 = *(const uint4*)pexSR;
    uint4 sS1 = *(const uint4*)(pexSR + 512);
    uint4 sR0 = *(const uint4*)pexRR;
    uint4 sR1 = *(const uint4*)(pexRR + 512);
    __builtin_amdgcn_s_setprio(1);
#pragma unroll
    for (int dt = 0; dt < 3; ++dt) {
      int d = ch * 96 + dt * 32 + l31;
      bf16x8 vo0 = *(const bf16x8*)&vl[swz64(d, (ch * 2 + 0) * 16 + hi * 8)];
      bf16x8 vo1 = *(const bf16x8*)&vl[swz64(d, (ch * 2 + 1) * 16 + hi * 8)];
      bf16x8 vs0 = *(const bf16x8*)&vl[swz64(d, ((1 - ch) * 2 + 0) * 16 + hi * 8)];
      bf16x8 vs1 = *(const bf16x8*)&vl[swz64(d, ((1 - ch) * 2 + 1) * 16 + hi * 8)];
      os[dt] = __builtin_amdgcn_mfma_f32_32x32x16_bf16(
          *(const bf16x8*)pS0, vo0, os[dt], 0, 0, 0);
      orl[dt] = __builtin_amdgcn_mfma_f32_32x32x16_bf16(
          *(const bf16x8*)pR0, vo0, orl[dt], 0, 0, 0);
      os[dt] = __builtin_amdgcn_mfma_f32_32x32x16_bf16(
          *(const bf16x8*)pS1, vo1, os[dt], 0, 0, 0);
      orl[dt] = __builtin_amdgcn_mfma_f32_32x32x16_bf16(
          *(const bf16x8*)pR1, vo1, orl[dt], 0, 0, 0);
      os[dt] = __builtin_amdgcn_mfma_f32_32x32x16_bf16(
          *(const bf16x8*)&sS0, vs0, os[dt], 0, 0, 0);
      orl[dt] = __builtin_amdgcn_mfma_f32_32x32x16_bf16(
          *(const bf16x8*)&sR0, vs0, orl[dt], 0, 0, 0);
      os[dt] = __builtin_amdgcn_mfma_f32_32x32x16_bf16(
          *(const bf16x8*)&sS1, vs1, os[dt], 0, 0, 0);
      orl[dt] = __builtin_amdgcn_mfma_f32_32x32x16_bf16(
          *(const bf16x8*)&sR1, vs1, orl[dt], 0, 0, 0);
    }
    __builtin_amdgcn_s_setprio(0);

    if (kt < 35) {
      // BC: PV + pex reads done; K(kt+1) landed (only outstanding glls)
      asm volatile("s_waitcnt vmcnt(0) lgkmcnt(0)\ns_barrier" ::: "memory");
      STAGE_V(kt + 1);           // flies under S(kt+1) + next A
      S_BLEND();                 // S(kt+1) -> frags (P for next PV)
      // D: S reads done + pex writes drained -> K region free, pex published
      asm volatile("s_waitcnt lgkmcnt(0)\ns_barrier" ::: "memory");
      if (kt + 2 < 36) STAGE_K(kt + 2);  // flies under PV(kt+1)
    }
  }

  // ---- epilogue: reduce lsum, blend, transpose, residual add, store ----
  lsum += __shfl_xor(lsum, 32);           // fold hi-half partner
  __syncthreads();                        // loop LDS traffic complete
  if (lane < 32) lred[(qh * 2 + ch) * 32 + l31] = lsum;
  __syncthreads();
  float linv[16];
#pragma unroll
  for (int r = 0; r < 16; ++r) {
    int m = (r & 3) + 8 * (r >> 2) + 4 * hi;
    float ltot = lred[(qh * 2 + 0) * 32 + m] + lred[(qh * 2 + 1) * 32 + m];
    linv[r] = c1f / ltot;
  }
  __syncthreads();                        // lred reads done before olds overlay
#pragma unroll
  for (int dt = 0; dt < 3; ++dt) {
    int d = ch * 96 + dt * 32 + l31;
#pragma unroll
    for (int r = 0; r < 16; ++r) {
      int m = (r & 3) + 8 * (r >> 2) + 4 * hi;
      int q = qh * 32 + m;
      olds[d * 64 + ((q & ~31) | ((q ^ d) & 31))] =
          os[dt][r] * linv[r] + c2f * orl[dt][r];
    }
  }
  __syncthreads();
  const float* xb = x + (size_t)b * CC * NN + qt * 64;
  float* ob = out + (size_t)b * CC * NN + qt * 64;
#pragma unroll
  for (int i = 0; i < 48; ++i) {
    int idx = i * 256 + t;
    int c = idx >> 6, nn = idx & 63;
    float v = olds[c * 64 + ((nn & ~31) | ((nn ^ c) & 31))];
    ob[(size_t)c * NN + nn] = v + xb[(size_t)c * NN + nn];
  }
#undef STAGE_K
#undef STAGE_V
#undef S_BLEND
}

// ---------------------------------------------------------------------------
extern "C" void kernel_launch(void* const* d_in, const int* in_sizes, int n_in,
                              void* d_out, int out_size, void* d_ws, size_t ws_size,
                              hipStream_t stream) {
  (void)in_sizes; (void)n_in; (void)out_size; (void)ws_size;
  const float* x   = (const float*)d_in[0];
  const float* lnw = (const float*)d_in[1];
  const float* lnb = (const float*)d_in[2];
  const float* Wq  = (const float*)d_in[3];
  const float* Wk  = (const float*)d_in[4];
  const float* Wv  = (const float*)d_in[5];
  const float* w1  = (const float*)d_in[6];
  const float* w2  = (const float*)d_in[7];
  float* out = (float*)d_out;

  u16* xn = (u16*)d_ws;
  size_t per = (size_t)NBATCH * NN * CC;
  u16* qb  = xn + per;
  u16* kb  = qb + per;
  u16* vtb = kb + per;

  ln_kernel<<<dim3(36, 16), 256, 0, stream>>>(x, lnw, lnb, xn);
  qkv_gemm<<<dim3(576, 3, 3), 256, 0, stream>>>(xn, Wq, Wk, Wv, qb, kb, vtb);
  attn_fused<<<dim3(576), 256, 0, stream>>>(qb, kb, vtb, w1, w2, x, out);
}